// Round 1
// baseline (6344.139 us; speedup 1.0000x reference)
//
#include <hip/hip_runtime.h>
#include <math.h>

#define HDIM 128
#define NGRAPH 256
#define EPSBN 1e-5f

// ---------- float<->ordered-uint encoding for atomic max ----------
__device__ inline unsigned enc_f(float v) {
  unsigned u = __float_as_uint(v);
  return (u & 0x80000000u) ? ~u : (u | 0x80000000u);
}
__device__ inline float dec_f(unsigned e) {
  return __uint_as_float((e & 0x80000000u) ? (e ^ 0x80000000u) : ~e);
}

// ---------- degree / dinv ----------
__global__ void k_deg(const int* __restrict__ dst, int* __restrict__ deg, int E) {
  int i = blockIdx.x * blockDim.x + threadIdx.x;
  if (i < E) atomicAdd(&deg[dst[i]], 1);
}

__global__ void k_dinv(const int* __restrict__ deg, float* __restrict__ dinv, int n) {
  int i = blockIdx.x * blockDim.x + threadIdx.x;
  if (i < n) dinv[i] = rsqrtf((float)deg[i] + 1.0f);
}

// ---------- 2-level exclusive scan of deg -> rowstart ----------
__global__ void k_scanA(const int* __restrict__ deg, int* __restrict__ rowstart,
                        int* __restrict__ bsum, int n) {
  __shared__ int s[256];
  int t = threadIdx.x, i = blockIdx.x * 256 + t;
  int v = (i < n) ? deg[i] : 0;
  s[t] = v;
  __syncthreads();
  for (int off = 1; off < 256; off <<= 1) {
    int x = (t >= off) ? s[t - off] : 0;
    __syncthreads();
    s[t] += x;
    __syncthreads();
  }
  if (i < n) rowstart[i] = s[t] - v;  // exclusive
  if (t == 255) bsum[blockIdx.x] = s[255];
}

__global__ void k_scanB(int* __restrict__ bsum, int nb) {
  __shared__ int s[512];
  int t = threadIdx.x;
  int v = (t < nb) ? bsum[t] : 0;
  s[t] = v;
  __syncthreads();
  for (int off = 1; off < 512; off <<= 1) {
    int x = (t >= off) ? s[t - off] : 0;
    __syncthreads();
    s[t] += x;
    __syncthreads();
  }
  if (t < nb) bsum[t] = s[t] - v;  // exclusive
}

__global__ void k_scanC(int* __restrict__ rowstart, const int* __restrict__ bsum,
                        int n, int E) {
  int i = blockIdx.x * 256 + threadIdx.x;
  if (i < n) rowstart[i] += bsum[blockIdx.x];
  if (i == 0) rowstart[n] = E;
}

__global__ void k_fill(const int* __restrict__ src, const int* __restrict__ dst,
                       const float* __restrict__ dinv, const int* __restrict__ rowstart,
                       int* __restrict__ cursor, int* __restrict__ csr_src,
                       float* __restrict__ csr_w, int E) {
  int e = blockIdx.x * blockDim.x + threadIdx.x;
  if (e < E) {
    int d = dst[e], s = src[e];
    int pos = rowstart[d] + atomicAdd(&cursor[d], 1);
    csr_src[pos] = s;
    csr_w[pos] = dinv[s] * dinv[d];
  }
}

// ---------- GEMM: out[N,128] = in[N,128] @ W[128,128] (+bias) ----------
// block: 256 threads, 64 rows, all 128 cols. K split into two 64-halves.
// LDS: Ws 64x128 (32KB) + hs 64x68-padded (17.4KB) -> 3 blocks/CU.
__global__ __launch_bounds__(256) void k_gemm(const float* __restrict__ in,
                                              const float* __restrict__ W,
                                              const float* __restrict__ bias,
                                              float* __restrict__ out, int n) {
  __shared__ float Ws[64 * 128];
  __shared__ float hs[64 * 68];
  int tid = threadIdx.x;
  int tx = tid & 15;   // col group: cols tx*4..+3 and 64+tx*4..+3
  int ty = tid >> 4;   // row group: rows ty + 16*i
  int row0 = blockIdx.x * 64;
  float acc[4][8];
#pragma unroll
  for (int i = 0; i < 4; i++)
#pragma unroll
    for (int j = 0; j < 8; j++) acc[i][j] = 0.f;

  for (int k0 = 0; k0 < 128; k0 += 64) {
    __syncthreads();
    // stage W k-half: 64x128 floats
    for (int idx = tid; idx < 64 * 128 / 4; idx += 256) {
      float4 v = ((const float4*)(W + k0 * 128))[idx];
      ((float4*)Ws)[idx] = v;
    }
    // stage h tile: 64 rows x 64 k, padded stride 68
    for (int idx = tid; idx < 64 * 64 / 4; idx += 256) {
      int r = idx >> 4;
      int c4 = idx & 15;
      int row = row0 + r;
      if (row >= n) row = n - 1;
      float4 v = *(const float4*)(in + (size_t)row * 128 + k0 + c4 * 4);
      *(float4*)(hs + r * 68 + c4 * 4) = v;
    }
    __syncthreads();
#pragma unroll
    for (int kk = 0; kk < 64; kk += 4) {
      float4 a[4];
#pragma unroll
      for (int i = 0; i < 4; i++) a[i] = *(const float4*)(hs + (ty + 16 * i) * 68 + kk);
#pragma unroll
      for (int kq = 0; kq < 4; kq++) {
        float4 b0 = *(const float4*)(Ws + (kk + kq) * 128 + tx * 4);
        float4 b1 = *(const float4*)(Ws + (kk + kq) * 128 + 64 + tx * 4);
#pragma unroll
        for (int i = 0; i < 4; i++) {
          float aa = ((const float*)&a[i])[kq];
          acc[i][0] += aa * b0.x; acc[i][1] += aa * b0.y;
          acc[i][2] += aa * b0.z; acc[i][3] += aa * b0.w;
          acc[i][4] += aa * b1.x; acc[i][5] += aa * b1.y;
          acc[i][6] += aa * b1.z; acc[i][7] += aa * b1.w;
        }
      }
    }
  }
#pragma unroll
  for (int i = 0; i < 4; i++) {
    int row = row0 + ty + 16 * i;
    if (row < n) {
      float4 o0 = make_float4(acc[i][0], acc[i][1], acc[i][2], acc[i][3]);
      float4 o1 = make_float4(acc[i][4], acc[i][5], acc[i][6], acc[i][7]);
      if (bias) {
        float4 bb0 = *(const float4*)(bias + tx * 4);
        float4 bb1 = *(const float4*)(bias + 64 + tx * 4);
        o0.x += bb0.x; o0.y += bb0.y; o0.z += bb0.z; o0.w += bb0.w;
        o1.x += bb1.x; o1.y += bb1.y; o1.z += bb1.z; o1.w += bb1.w;
      }
      *(float4*)(out + (size_t)row * 128 + tx * 4) = o0;
      *(float4*)(out + (size_t)row * 128 + 64 + tx * 4) = o1;
    }
  }
}

// ---------- edge aggregation: out[n] = sum_e w_e*hw[src] + dinv[n]^2*hw[n] + b ----------
__global__ __launch_bounds__(256) void k_agg(const float* __restrict__ hw,
                                             const int* __restrict__ rowstart,
                                             const int* __restrict__ csr_src,
                                             const float* __restrict__ csr_w,
                                             const float* __restrict__ dinv,
                                             const float* __restrict__ bias,
                                             float* __restrict__ out, int n) {
  int wave = threadIdx.x >> 6;
  int lane = threadIdx.x & 63;
  int node = blockIdx.x * 4 + wave;
  if (node >= n) return;
  int e0 = rowstart[node], e1 = rowstart[node + 1];
  float ax = 0.f, ay = 0.f;
  for (int e = e0; e < e1; ++e) {
    int s = csr_src[e];
    float w = csr_w[e];
    float2 v = *(const float2*)(hw + (size_t)s * 128 + lane * 2);
    ax += w * v.x;
    ay += w * v.y;
  }
  float dn = dinv[node];
  float sn = dn * dn;
  float2 v = *(const float2*)(hw + (size_t)node * 128 + lane * 2);
  float2 bb = *(const float2*)(bias + lane * 2);
  ax += sn * v.x + bb.x;
  ay += sn * v.y + bb.y;
  float2 o = make_float2(ax, ay);
  *(float2*)(out + (size_t)node * 128 + lane * 2) = o;
}

// ---------- column stats (two-stage, deterministic) ----------
__global__ __launch_bounds__(256) void k_colstats(const float* __restrict__ x,
                                                  float* __restrict__ psum,
                                                  float* __restrict__ psq, int n) {
  int c = threadIdx.x & 127;
  int half = threadIdx.x >> 7;
  float s = 0.f, q = 0.f;
  for (int r = blockIdx.x * 2 + half; r < n; r += gridDim.x * 2) {
    float v = x[(size_t)r * 128 + c];
    s += v;
    q += v * v;
  }
  __shared__ float ls[128], lq[128];
  if (half == 1) { ls[c] = s; lq[c] = q; }
  __syncthreads();
  if (half == 0) {
    psum[blockIdx.x * 128 + c] = s + ls[c];
    psq[blockIdx.x * 128 + c] = q + lq[c];
  }
}

__global__ void k_bnfin(const float* __restrict__ psum, const float* __restrict__ psq,
                        const float* __restrict__ g, const float* __restrict__ be,
                        float* __restrict__ scale, float* __restrict__ shift,
                        int nblocks, int n) {
  int c = threadIdx.x;  // 128 threads
  float s = 0.f, q = 0.f;
  for (int b = 0; b < nblocks; b++) {
    s += psum[b * 128 + c];
    q += psq[b * 128 + c];
  }
  float mu = s / (float)n;
  float var = q / (float)n - mu * mu;
  float rs = rsqrtf(var + EPSBN);
  float sc = g[c] * rs;
  scale[c] = sc;
  shift[c] = be[c] - mu * sc;
}

// ---------- BN apply (+relu | +residual) ----------
template <int RELU, int RESID>
__global__ __launch_bounds__(256) void k_bnapply(const float* __restrict__ x,
                                                 const float* __restrict__ scale,
                                                 const float* __restrict__ shift,
                                                 float* __restrict__ out, int n) {
  int idx = blockIdx.x * 256 + threadIdx.x;  // float4 index
  int total = n * 32;
  if (idx >= total) return;
  int c4 = idx & 31;
  float4 v = ((const float4*)x)[idx];
  float4 sc = ((const float4*)scale)[c4];
  float4 sh = ((const float4*)shift)[c4];
  float4 o;
  o.x = v.x * sc.x + sh.x;
  o.y = v.y * sc.y + sh.y;
  o.z = v.z * sc.z + sh.z;
  o.w = v.w * sc.w + sh.w;
  if (RELU) {
    o.x = fmaxf(o.x, 0.f); o.y = fmaxf(o.y, 0.f);
    o.z = fmaxf(o.z, 0.f); o.w = fmaxf(o.w, 0.f);
  }
  if (RESID) {
    float4 h = ((const float4*)out)[idx];
    o.x += h.x; o.y += h.y; o.z += h.z; o.w += h.w;
  }
  ((float4*)out)[idx] = o;
}

// ---------- pooling ----------
__global__ __launch_bounds__(256) void k_pool(const float* __restrict__ h,
                                              const int* __restrict__ batch,
                                              float* __restrict__ sums,
                                              unsigned* __restrict__ maxenc,
                                              int* __restrict__ cnt, int n) {
  int wave = threadIdx.x >> 6;
  int lane = threadIdx.x & 63;
  int node = blockIdx.x * 4 + wave;
  if (node >= n) return;
  int b = batch[node];
  float2 v = *(const float2*)(h + (size_t)node * 128 + lane * 2);
  atomicAdd(&sums[b * 128 + lane * 2], v.x);
  atomicAdd(&sums[b * 128 + lane * 2 + 1], v.y);
  atomicMax(&maxenc[b * 128 + lane * 2], enc_f(v.x));
  atomicMax(&maxenc[b * 128 + lane * 2 + 1], enc_f(v.y));
  if (lane == 0) atomicAdd(&cnt[b], 1);
}

// ---------- readout MLP: [mean|max|sum](384) -> 256 -> 128 -> 1 ----------
__global__ __launch_bounds__(256) void k_readout(const float* __restrict__ sums,
                                                 const unsigned* __restrict__ maxenc,
                                                 const int* __restrict__ cnt,
                                                 const float* __restrict__ Wa,
                                                 const float* __restrict__ ba,
                                                 const float* __restrict__ Wb,
                                                 const float* __restrict__ bb,
                                                 const float* __restrict__ Wc,
                                                 const float* __restrict__ bc,
                                                 float* __restrict__ out) {
  int g = blockIdx.x;
  int t = threadIdx.x;
  __shared__ float z[384];
  __shared__ float za[256];
  __shared__ float zb[128];
  float c = (float)(cnt[g] > 1 ? cnt[g] : 1);
  if (t < 128) {
    float s = sums[g * 128 + t];
    z[t] = s / c;
    z[128 + t] = dec_f(maxenc[g * 128 + t]);
    z[256 + t] = s;
  }
  __syncthreads();
  float accA = ba[t];
  for (int k = 0; k < 384; k++) accA += z[k] * Wa[k * 256 + t];
  za[t] = fmaxf(accA, 0.f);
  __syncthreads();
  if (t < 128) {
    float accB = bb[t];
    for (int k = 0; k < 256; k++) accB += za[k] * Wb[k * 128 + t];
    zb[t] = fmaxf(accB, 0.f);
  }
  __syncthreads();
  if (t < 64) {
    float p = zb[t] * Wc[t] + zb[t + 64] * Wc[t + 64];
    for (int off = 32; off > 0; off >>= 1) p += __shfl_down(p, off);
    if (t == 0) out[g] = p + bc[0];
  }
}

extern "C" void kernel_launch(void* const* d_in, const int* in_sizes, int n_in,
                              void* d_out, int out_size, void* d_ws, size_t ws_size,
                              hipStream_t stream) {
  const float* x   = (const float*)d_in[0];
  const int* edge  = (const int*)d_in[1];
  const int* batch = (const int*)d_in[2];
  const float* Wp  = (const float*)d_in[3];
  const float* bp  = (const float*)d_in[4];
  const float* W1  = (const float*)d_in[5];
  const float* b1  = (const float*)d_in[6];
  const float* g1  = (const float*)d_in[7];
  const float* be1 = (const float*)d_in[8];
  const float* W2  = (const float*)d_in[9];
  const float* b2  = (const float*)d_in[10];
  const float* g2  = (const float*)d_in[11];
  const float* be2 = (const float*)d_in[12];
  const float* Wa  = (const float*)d_in[13];
  const float* ba  = (const float*)d_in[14];
  const float* Wb  = (const float*)d_in[15];
  const float* bbp = (const float*)d_in[16];
  const float* Wc  = (const float*)d_in[17];
  const float* bc  = (const float*)d_in[18];
  float* out = (float*)d_out;

  const int N = in_sizes[0] / 128;
  const int E = in_sizes[1] / 2;
  const int* esrc = edge;
  const int* edst = edge + E;

  // workspace carve
  char* p = (char*)d_ws;
  auto carve = [&](size_t bytes) {
    char* r = p;
    p += (bytes + 255) & ~(size_t)255;
    return (void*)r;
  };
  float* h   = (float*)carve((size_t)N * 128 * 4);
  float* t1  = (float*)carve((size_t)N * 128 * 4);
  float* t2  = (float*)carve((size_t)N * 128 * 4);
  int* csr_src = (int*)carve((size_t)E * 4);
  float* csr_w = (float*)carve((size_t)E * 4);
  int* deg     = (int*)carve((size_t)N * 4);
  float* dinv  = (float*)carve((size_t)N * 4);
  int* rowstart = (int*)carve((size_t)(N + 1) * 4);
  int* cursor   = (int*)carve((size_t)N * 4);
  int* bsum     = (int*)carve(512 * 4);
  float* psum   = (float*)carve(256 * 128 * 4);
  float* psq    = (float*)carve(256 * 128 * 4);
  float* scale  = (float*)carve(128 * 4);
  float* shift  = (float*)carve(128 * 4);
  float* pools  = (float*)carve((size_t)NGRAPH * 128 * 4);
  unsigned* poolm = (unsigned*)carve((size_t)NGRAPH * 128 * 4);
  int* poolc      = (int*)carve(NGRAPH * 4);

  const int NB = (N + 255) / 256;  // scan blocks (391)

  hipMemsetAsync(deg, 0, (size_t)N * 4, stream);
  hipMemsetAsync(cursor, 0, (size_t)N * 4, stream);
  hipMemsetAsync(pools, 0, (size_t)NGRAPH * 128 * 4, stream);
  hipMemsetAsync(poolm, 0, (size_t)NGRAPH * 128 * 4, stream);
  hipMemsetAsync(poolc, 0, (size_t)NGRAPH * 4, stream);

  k_deg<<<(E + 255) / 256, 256, 0, stream>>>(edst, deg, E);
  k_dinv<<<NB, 256, 0, stream>>>(deg, dinv, N);
  k_scanA<<<NB, 256, 0, stream>>>(deg, rowstart, bsum, N);
  k_scanB<<<1, 512, 0, stream>>>(bsum, NB);
  k_scanC<<<NB, 256, 0, stream>>>(rowstart, bsum, N, E);
  k_fill<<<(E + 255) / 256, 256, 0, stream>>>(esrc, edst, dinv, rowstart, cursor,
                                              csr_src, csr_w, E);

  const int GB = (N + 63) / 64;    // gemm blocks
  const int AB = (N + 3) / 4;      // agg/pool blocks
  const int EB = (N * 32 + 255) / 256;  // elementwise blocks (float4)

  k_gemm<<<GB, 256, 0, stream>>>(x, Wp, bp, h, N);

  for (int l = 0; l < 8; l++) {
    k_gemm<<<GB, 256, 0, stream>>>(h, W1 + (size_t)l * 128 * 128, nullptr, t1, N);
    k_agg<<<AB, 256, 0, stream>>>(t1, rowstart, csr_src, csr_w, dinv, b1 + l * 128, t2, N);
    k_colstats<<<256, 256, 0, stream>>>(t2, psum, psq, N);
    k_bnfin<<<1, 128, 0, stream>>>(psum, psq, g1 + l * 128, be1 + l * 128, scale, shift, 256, N);
    k_bnapply<1, 0><<<EB, 256, 0, stream>>>(t2, scale, shift, t1, N);

    k_gemm<<<GB, 256, 0, stream>>>(t1, W2 + (size_t)l * 128 * 128, nullptr, t2, N);
    k_agg<<<AB, 256, 0, stream>>>(t2, rowstart, csr_src, csr_w, dinv, b2 + l * 128, t1, N);
    k_colstats<<<256, 256, 0, stream>>>(t1, psum, psq, N);
    k_bnfin<<<1, 128, 0, stream>>>(psum, psq, g2 + l * 128, be2 + l * 128, scale, shift, 256, N);
    k_bnapply<0, 1><<<EB, 256, 0, stream>>>(t1, scale, shift, h, N);
  }

  k_pool<<<AB, 256, 0, stream>>>(h, batch, pools, poolm, poolc, N);
  k_readout<<<NGRAPH, 256, 0, stream>>>(pools, poolm, poolc, Wa, ba, Wb, bbp, Wc, bc, out);
}

// Round 2
// 5439.846 us; speedup vs baseline: 1.1662x; 1.1662x over previous
//
#include <hip/hip_runtime.h>
#include <math.h>
#include <float.h>

#define HDIM 128
#define NGRAPH 256
#define EPSBN 1e-5f

// ---------- float<->ordered-uint encoding for atomic max ----------
__device__ inline unsigned enc_f(float v) {
  unsigned u = __float_as_uint(v);
  return (u & 0x80000000u) ? ~u : (u | 0x80000000u);
}
__device__ inline float dec_f(unsigned e) {
  return __uint_as_float((e & 0x80000000u) ? (e ^ 0x80000000u) : ~e);
}

// ---------- degree / dinv ----------
__global__ void k_deg(const int* __restrict__ dst, int* __restrict__ deg, int E) {
  int i = blockIdx.x * blockDim.x + threadIdx.x;
  if (i < E) atomicAdd(&deg[dst[i]], 1);
}

__global__ void k_dinv(const int* __restrict__ deg, float* __restrict__ dinv, int n) {
  int i = blockIdx.x * blockDim.x + threadIdx.x;
  if (i < n) dinv[i] = rsqrtf((float)deg[i] + 1.0f);
}

// ---------- 2-level exclusive scan of deg -> rowstart ----------
__global__ void k_scanA(const int* __restrict__ deg, int* __restrict__ rowstart,
                        int* __restrict__ bsum, int n) {
  __shared__ int s[256];
  int t = threadIdx.x, i = blockIdx.x * 256 + t;
  int v = (i < n) ? deg[i] : 0;
  s[t] = v;
  __syncthreads();
  for (int off = 1; off < 256; off <<= 1) {
    int x = (t >= off) ? s[t - off] : 0;
    __syncthreads();
    s[t] += x;
    __syncthreads();
  }
  if (i < n) rowstart[i] = s[t] - v;  // exclusive
  if (t == 255) bsum[blockIdx.x] = s[255];
}

__global__ void k_scanB(int* __restrict__ bsum, int nb) {
  __shared__ int s[512];
  int t = threadIdx.x;
  int v = (t < nb) ? bsum[t] : 0;
  s[t] = v;
  __syncthreads();
  for (int off = 1; off < 512; off <<= 1) {
    int x = (t >= off) ? s[t - off] : 0;
    __syncthreads();
    s[t] += x;
    __syncthreads();
  }
  if (t < nb) bsum[t] = s[t] - v;  // exclusive
}

__global__ void k_scanC(int* __restrict__ rowstart, const int* __restrict__ bsum,
                        int n, int E) {
  int i = blockIdx.x * 256 + threadIdx.x;
  if (i < n) rowstart[i] += bsum[blockIdx.x];
  if (i == 0) rowstart[n] = E;
}

__global__ void k_fill(const int* __restrict__ src, const int* __restrict__ dst,
                       const float* __restrict__ dinv, const int* __restrict__ rowstart,
                       int* __restrict__ cursor, int* __restrict__ csr_src,
                       float* __restrict__ csr_w, int E) {
  int e = blockIdx.x * blockDim.x + threadIdx.x;
  if (e < E) {
    int d = dst[e], s = src[e];
    int pos = rowstart[d] + atomicAdd(&cursor[d], 1);
    csr_src[pos] = s;
    csr_w[pos] = dinv[s] * dinv[d];
  }
}

// ---------- GEMM: out[N,128] = xform(in)[N,128] @ W[128,128] (+bias) ----------
// XFORM=1: in := relu(in*scale+shift) applied during LDS staging (fused BN+ReLU).
// block: 256 threads, 64 rows, all 128 cols. K split into two 64-halves.
template <int XFORM>
__global__ __launch_bounds__(256) void k_gemm(const float* __restrict__ in,
                                              const float* __restrict__ W,
                                              const float* __restrict__ bias,
                                              const float* __restrict__ scale,
                                              const float* __restrict__ shift,
                                              float* __restrict__ out, int n) {
  __shared__ float Ws[64 * 128];
  __shared__ float hs[64 * 68];
  int tid = threadIdx.x;
  int tx = tid & 15;   // col group: cols tx*4..+3 and 64+tx*4..+3
  int ty = tid >> 4;   // row group: rows ty + 16*i
  int row0 = blockIdx.x * 64;
  float acc[4][8];
#pragma unroll
  for (int i = 0; i < 4; i++)
#pragma unroll
    for (int j = 0; j < 8; j++) acc[i][j] = 0.f;

  for (int k0 = 0; k0 < 128; k0 += 64) {
    __syncthreads();
    // stage W k-half: 64x128 floats
    for (int idx = tid; idx < 64 * 128 / 4; idx += 256) {
      float4 v = ((const float4*)(W + k0 * 128))[idx];
      ((float4*)Ws)[idx] = v;
    }
    // stage h tile: 64 rows x 64 k, padded stride 68
    for (int idx = tid; idx < 64 * 64 / 4; idx += 256) {
      int r = idx >> 4;
      int c4 = idx & 15;
      int row = row0 + r;
      if (row >= n) row = n - 1;
      float4 v = *(const float4*)(in + (size_t)row * 128 + k0 + c4 * 4);
      if (XFORM) {
        float4 sc = *(const float4*)(scale + k0 + c4 * 4);
        float4 sh = *(const float4*)(shift + k0 + c4 * 4);
        v.x = fmaxf(v.x * sc.x + sh.x, 0.f);
        v.y = fmaxf(v.y * sc.y + sh.y, 0.f);
        v.z = fmaxf(v.z * sc.z + sh.z, 0.f);
        v.w = fmaxf(v.w * sc.w + sh.w, 0.f);
      }
      *(float4*)(hs + r * 68 + c4 * 4) = v;
    }
    __syncthreads();
#pragma unroll
    for (int kk = 0; kk < 64; kk += 4) {
      float4 a[4];
#pragma unroll
      for (int i = 0; i < 4; i++) a[i] = *(const float4*)(hs + (ty + 16 * i) * 68 + kk);
#pragma unroll
      for (int kq = 0; kq < 4; kq++) {
        float4 b0 = *(const float4*)(Ws + (kk + kq) * 128 + tx * 4);
        float4 b1 = *(const float4*)(Ws + (kk + kq) * 128 + 64 + tx * 4);
#pragma unroll
        for (int i = 0; i < 4; i++) {
          float aa = ((const float*)&a[i])[kq];
          acc[i][0] += aa * b0.x; acc[i][1] += aa * b0.y;
          acc[i][2] += aa * b0.z; acc[i][3] += aa * b0.w;
          acc[i][4] += aa * b1.x; acc[i][5] += aa * b1.y;
          acc[i][6] += aa * b1.z; acc[i][7] += aa * b1.w;
        }
      }
    }
  }
#pragma unroll
  for (int i = 0; i < 4; i++) {
    int row = row0 + ty + 16 * i;
    if (row < n) {
      float4 o0 = make_float4(acc[i][0], acc[i][1], acc[i][2], acc[i][3]);
      float4 o1 = make_float4(acc[i][4], acc[i][5], acc[i][6], acc[i][7]);
      if (bias) {
        float4 bb0 = *(const float4*)(bias + tx * 4);
        float4 bb1 = *(const float4*)(bias + 64 + tx * 4);
        o0.x += bb0.x; o0.y += bb0.y; o0.z += bb0.z; o0.w += bb0.w;
        o1.x += bb1.x; o1.y += bb1.y; o1.z += bb1.z; o1.w += bb1.w;
      }
      *(float4*)(out + (size_t)row * 128 + tx * 4) = o0;
      *(float4*)(out + (size_t)row * 128 + 64 + tx * 4) = o1;
    }
  }
}

// ---------- edge aggregation: out[n] = sum_e w_e*hw[src] + dinv[n]^2*hw[n] + b ----------
__global__ __launch_bounds__(256) void k_agg(const float* __restrict__ hw,
                                             const int* __restrict__ rowstart,
                                             const int* __restrict__ csr_src,
                                             const float* __restrict__ csr_w,
                                             const float* __restrict__ dinv,
                                             const float* __restrict__ bias,
                                             float* __restrict__ out, int n) {
  int wave = threadIdx.x >> 6;
  int lane = threadIdx.x & 63;
  int node = blockIdx.x * 4 + wave;
  if (node >= n) return;
  int e0 = rowstart[node], e1 = rowstart[node + 1];
  float ax0 = 0.f, ay0 = 0.f, ax1 = 0.f, ay1 = 0.f;
  int e = e0;
  for (; e + 1 < e1; e += 2) {
    int s0 = csr_src[e];
    int s1 = csr_src[e + 1];
    float w0 = csr_w[e];
    float w1 = csr_w[e + 1];
    float2 v0 = *(const float2*)(hw + (size_t)s0 * 128 + lane * 2);
    float2 v1 = *(const float2*)(hw + (size_t)s1 * 128 + lane * 2);
    ax0 += w0 * v0.x; ay0 += w0 * v0.y;
    ax1 += w1 * v1.x; ay1 += w1 * v1.y;
  }
  if (e < e1) {
    int s0 = csr_src[e];
    float w0 = csr_w[e];
    float2 v0 = *(const float2*)(hw + (size_t)s0 * 128 + lane * 2);
    ax0 += w0 * v0.x; ay0 += w0 * v0.y;
  }
  float ax = ax0 + ax1, ay = ay0 + ay1;
  float dn = dinv[node];
  float sn = dn * dn;
  float2 v = *(const float2*)(hw + (size_t)node * 128 + lane * 2);
  float2 bb = *(const float2*)(bias + lane * 2);
  ax += sn * v.x + bb.x;
  ay += sn * v.y + bb.y;
  float2 o = make_float2(ax, ay);
  *(float2*)(out + (size_t)node * 128 + lane * 2) = o;
}

// ---------- column stats (two-stage, deterministic) ----------
__global__ __launch_bounds__(256) void k_colstats(const float* __restrict__ x,
                                                  float* __restrict__ psum,
                                                  float* __restrict__ psq, int n) {
  int c = threadIdx.x & 127;
  int half = threadIdx.x >> 7;
  float s = 0.f, q = 0.f;
  for (int r = blockIdx.x * 2 + half; r < n; r += gridDim.x * 2) {
    float v = x[(size_t)r * 128 + c];
    s += v;
    q += v * v;
  }
  __shared__ float ls[128], lq[128];
  if (half == 1) { ls[c] = s; lq[c] = q; }
  __syncthreads();
  if (half == 0) {
    psum[blockIdx.x * 128 + c] = s + ls[c];
    psq[blockIdx.x * 128 + c] = q + lq[c];
  }
}

__global__ void k_bnfin(const float* __restrict__ psum, const float* __restrict__ psq,
                        const float* __restrict__ g, const float* __restrict__ be,
                        float* __restrict__ scale, float* __restrict__ shift,
                        int nblocks, int n) {
  int c = threadIdx.x;  // 128 threads
  float s = 0.f, q = 0.f;
  for (int b = 0; b < nblocks; b++) {
    s += psum[b * 128 + c];
    q += psq[b * 128 + c];
  }
  float mu = s / (float)n;
  float var = q / (float)n - mu * mu;
  float rs = rsqrtf(var + EPSBN);
  float sc = g[c] * rs;
  scale[c] = sc;
  shift[c] = be[c] - mu * sc;
}

// ---------- BN apply + residual: out += x*scale+shift ----------
__global__ __launch_bounds__(256) void k_bnresid(const float* __restrict__ x,
                                                 const float* __restrict__ scale,
                                                 const float* __restrict__ shift,
                                                 float* __restrict__ out, int n) {
  int idx = blockIdx.x * 256 + threadIdx.x;  // float4 index
  int total = n * 32;
  if (idx >= total) return;
  int c4 = idx & 31;
  float4 v = ((const float4*)x)[idx];
  float4 sc = ((const float4*)scale)[c4];
  float4 sh = ((const float4*)shift)[c4];
  float4 h = ((const float4*)out)[idx];
  float4 o;
  o.x = v.x * sc.x + sh.x + h.x;
  o.y = v.y * sc.y + sh.y + h.y;
  o.z = v.z * sc.z + sh.z + h.z;
  o.w = v.w * sc.w + sh.w + h.w;
  ((float4*)out)[idx] = o;
}

// ---------- pooling: batch is SORTED -> segment reduction, flush at boundaries ----------
#define PCHUNK 128
__global__ __launch_bounds__(128) void k_pool(const float* __restrict__ h,
                                              const int* __restrict__ batch,
                                              float* __restrict__ sums,
                                              unsigned* __restrict__ maxenc,
                                              int* __restrict__ cnt, int n) {
  int c = threadIdx.x;  // column 0..127
  int start = blockIdx.x * PCHUNK;
  if (start >= n) return;
  int end = start + PCHUNK;
  if (end > n) end = n;
  int cur = batch[start];
  float s = 0.f, mx = -FLT_MAX;
  int runlen = 0;
  for (int i = start; i < end; ++i) {
    int b = batch[i];
    if (b != cur) {
      atomicAdd(&sums[cur * 128 + c], s);
      atomicMax(&maxenc[cur * 128 + c], enc_f(mx));
      if (c == 0) atomicAdd(&cnt[cur], runlen);
      s = 0.f; mx = -FLT_MAX; runlen = 0; cur = b;
    }
    float v = h[(size_t)i * 128 + c];
    s += v;
    mx = fmaxf(mx, v);
    runlen++;
  }
  atomicAdd(&sums[cur * 128 + c], s);
  atomicMax(&maxenc[cur * 128 + c], enc_f(mx));
  if (c == 0) atomicAdd(&cnt[cur], runlen);
}

// ---------- readout MLP: [mean|max|sum](384) -> 256 -> 128 -> 1 ----------
__global__ __launch_bounds__(256) void k_readout(const float* __restrict__ sums,
                                                 const unsigned* __restrict__ maxenc,
                                                 const int* __restrict__ cnt,
                                                 const float* __restrict__ Wa,
                                                 const float* __restrict__ ba,
                                                 const float* __restrict__ Wb,
                                                 const float* __restrict__ bb,
                                                 const float* __restrict__ Wc,
                                                 const float* __restrict__ bc,
                                                 float* __restrict__ out) {
  int g = blockIdx.x;
  int t = threadIdx.x;
  __shared__ float z[384];
  __shared__ float za[256];
  __shared__ float zb[128];
  float c = (float)(cnt[g] > 1 ? cnt[g] : 1);
  if (t < 128) {
    float s = sums[g * 128 + t];
    z[t] = s / c;
    z[128 + t] = dec_f(maxenc[g * 128 + t]);
    z[256 + t] = s;
  }
  __syncthreads();
  float accA = ba[t];
  for (int k = 0; k < 384; k++) accA += z[k] * Wa[k * 256 + t];
  za[t] = fmaxf(accA, 0.f);
  __syncthreads();
  if (t < 128) {
    float accB = bb[t];
    for (int k = 0; k < 256; k++) accB += za[k] * Wb[k * 128 + t];
    zb[t] = fmaxf(accB, 0.f);
  }
  __syncthreads();
  if (t < 64) {
    float p = zb[t] * Wc[t] + zb[t + 64] * Wc[t + 64];
    for (int off = 32; off > 0; off >>= 1) p += __shfl_down(p, off);
    if (t == 0) out[g] = p + bc[0];
  }
}

extern "C" void kernel_launch(void* const* d_in, const int* in_sizes, int n_in,
                              void* d_out, int out_size, void* d_ws, size_t ws_size,
                              hipStream_t stream) {
  const float* x   = (const float*)d_in[0];
  const int* edge  = (const int*)d_in[1];
  const int* batch = (const int*)d_in[2];
  const float* Wp  = (const float*)d_in[3];
  const float* bp  = (const float*)d_in[4];
  const float* W1  = (const float*)d_in[5];
  const float* b1  = (const float*)d_in[6];
  const float* g1  = (const float*)d_in[7];
  const float* be1 = (const float*)d_in[8];
  const float* W2  = (const float*)d_in[9];
  const float* b2  = (const float*)d_in[10];
  const float* g2  = (const float*)d_in[11];
  const float* be2 = (const float*)d_in[12];
  const float* Wa  = (const float*)d_in[13];
  const float* ba  = (const float*)d_in[14];
  const float* Wb  = (const float*)d_in[15];
  const float* bbp = (const float*)d_in[16];
  const float* Wc  = (const float*)d_in[17];
  const float* bc  = (const float*)d_in[18];
  float* out = (float*)d_out;

  const int N = in_sizes[0] / 128;
  const int E = in_sizes[1] / 2;
  const int* esrc = edge;
  const int* edst = edge + E;

  // workspace carve
  char* p = (char*)d_ws;
  auto carve = [&](size_t bytes) {
    char* r = p;
    p += (bytes + 255) & ~(size_t)255;
    return (void*)r;
  };
  float* h   = (float*)carve((size_t)N * 128 * 4);
  float* t1  = (float*)carve((size_t)N * 128 * 4);
  float* t2  = (float*)carve((size_t)N * 128 * 4);
  int* csr_src = (int*)carve((size_t)E * 4);
  float* csr_w = (float*)carve((size_t)E * 4);
  int* deg     = (int*)carve((size_t)N * 4);
  float* dinv  = (float*)carve((size_t)N * 4);
  int* rowstart = (int*)carve((size_t)(N + 1) * 4);
  int* cursor   = (int*)carve((size_t)N * 4);
  int* bsum     = (int*)carve(512 * 4);
  float* psum   = (float*)carve(256 * 128 * 4);
  float* psq    = (float*)carve(256 * 128 * 4);
  float* scale  = (float*)carve(128 * 4);
  float* shift  = (float*)carve(128 * 4);
  float* pools  = (float*)carve((size_t)NGRAPH * 128 * 4);
  unsigned* poolm = (unsigned*)carve((size_t)NGRAPH * 128 * 4);
  int* poolc      = (int*)carve(NGRAPH * 4);

  const int NB = (N + 255) / 256;  // scan blocks

  hipMemsetAsync(deg, 0, (size_t)N * 4, stream);
  hipMemsetAsync(cursor, 0, (size_t)N * 4, stream);
  hipMemsetAsync(pools, 0, (size_t)NGRAPH * 128 * 4, stream);
  hipMemsetAsync(poolm, 0, (size_t)NGRAPH * 128 * 4, stream);
  hipMemsetAsync(poolc, 0, (size_t)NGRAPH * 4, stream);

  k_deg<<<(E + 255) / 256, 256, 0, stream>>>(edst, deg, E);
  k_dinv<<<NB, 256, 0, stream>>>(deg, dinv, N);
  k_scanA<<<NB, 256, 0, stream>>>(deg, rowstart, bsum, N);
  k_scanB<<<1, 512, 0, stream>>>(bsum, NB);
  k_scanC<<<NB, 256, 0, stream>>>(rowstart, bsum, N, E);
  k_fill<<<(E + 255) / 256, 256, 0, stream>>>(esrc, edst, dinv, rowstart, cursor,
                                              csr_src, csr_w, E);

  const int GB = (N + 63) / 64;    // gemm blocks
  const int AB = (N + 3) / 4;      // agg blocks
  const int EB = (N * 32 + 255) / 256;  // elementwise blocks (float4)
  const int PB = (N + PCHUNK - 1) / PCHUNK;

  k_gemm<0><<<GB, 256, 0, stream>>>(x, Wp, bp, nullptr, nullptr, h, N);

  for (int l = 0; l < 8; l++) {
    // o1 = gcn1(h); bn1 stats
    k_gemm<0><<<GB, 256, 0, stream>>>(h, W1 + (size_t)l * 128 * 128, nullptr, nullptr, nullptr, t1, N);
    k_agg<<<AB, 256, 0, stream>>>(t1, rowstart, csr_src, csr_w, dinv, b1 + l * 128, t2, N);
    k_colstats<<<256, 256, 0, stream>>>(t2, psum, psq, N);
    k_bnfin<<<1, 128, 0, stream>>>(psum, psq, g1 + l * 128, be1 + l * 128, scale, shift, 256, N);
    // o2 = gcn2(relu(bn1(t2)))  -- BN+ReLU fused into gemm input staging
    k_gemm<1><<<GB, 256, 0, stream>>>(t2, W2 + (size_t)l * 128 * 128, nullptr, scale, shift, t1, N);
    k_agg<<<AB, 256, 0, stream>>>(t1, rowstart, csr_src, csr_w, dinv, b2 + l * 128, t2, N);
    k_colstats<<<256, 256, 0, stream>>>(t2, psum, psq, N);
    k_bnfin<<<1, 128, 0, stream>>>(psum, psq, g2 + l * 128, be2 + l * 128, scale, shift, 256, N);
    // h += bn2(t2)
    k_bnresid<<<EB, 256, 0, stream>>>(t2, scale, shift, h, N);
  }

  k_pool<<<PB, 128, 0, stream>>>(h, batch, pools, poolm, poolc, N);
  k_readout<<<NGRAPH, 256, 0, stream>>>(pools, poolm, poolc, Wa, ba, Wb, bbp, Wc, bc, out);
}

// Round 3
// 4670.268 us; speedup vs baseline: 1.3584x; 1.1648x over previous
//
#include <hip/hip_runtime.h>
#include <hip/hip_fp16.h>
#include <math.h>
#include <float.h>

#define HDIM 128
#define NGRAPH 256
#define EPSBN 1e-5f

// ---------- float<->ordered-uint encoding for atomic max ----------
__device__ inline unsigned enc_f(float v) {
  unsigned u = __float_as_uint(v);
  return (u & 0x80000000u) ? ~u : (u | 0x80000000u);
}
__device__ inline float dec_f(unsigned e) {
  return __uint_as_float((e & 0x80000000u) ? (e ^ 0x80000000u) : ~e);
}

// ---------- degree / dinv ----------
__global__ void k_deg(const int* __restrict__ dst, int* __restrict__ deg, int E) {
  int i = blockIdx.x * blockDim.x + threadIdx.x;
  if (i < E) atomicAdd(&deg[dst[i]], 1);
}

__global__ void k_dinv(const int* __restrict__ deg, float* __restrict__ dinv, int n) {
  int i = blockIdx.x * blockDim.x + threadIdx.x;
  if (i < n) dinv[i] = rsqrtf((float)deg[i] + 1.0f);
}

// ---------- 2-level exclusive scan of deg -> rowstart ----------
__global__ void k_scanA(const int* __restrict__ deg, int* __restrict__ rowstart,
                        int* __restrict__ bsum, int n) {
  __shared__ int s[256];
  int t = threadIdx.x, i = blockIdx.x * 256 + t;
  int v = (i < n) ? deg[i] : 0;
  s[t] = v;
  __syncthreads();
  for (int off = 1; off < 256; off <<= 1) {
    int x = (t >= off) ? s[t - off] : 0;
    __syncthreads();
    s[t] += x;
    __syncthreads();
  }
  if (i < n) rowstart[i] = s[t] - v;  // exclusive
  if (t == 255) bsum[blockIdx.x] = s[255];
}

__global__ void k_scanB(int* __restrict__ bsum, int nb) {
  __shared__ int s[512];
  int t = threadIdx.x;
  int v = (t < nb) ? bsum[t] : 0;
  s[t] = v;
  __syncthreads();
  for (int off = 1; off < 512; off <<= 1) {
    int x = (t >= off) ? s[t - off] : 0;
    __syncthreads();
    s[t] += x;
    __syncthreads();
  }
  if (t < nb) bsum[t] = s[t] - v;  // exclusive
}

__global__ void k_scanC(int* __restrict__ rowstart, const int* __restrict__ bsum,
                        int n, int E) {
  int i = blockIdx.x * 256 + threadIdx.x;
  if (i < n) rowstart[i] += bsum[blockIdx.x];
  if (i == 0) rowstart[n] = E;
}

__global__ void k_fill(const int* __restrict__ src, const int* __restrict__ dst,
                       const float* __restrict__ dinv, const int* __restrict__ rowstart,
                       int* __restrict__ cursor, int* __restrict__ csr_src,
                       float* __restrict__ csr_w, int E) {
  int e = blockIdx.x * blockDim.x + threadIdx.x;
  if (e < E) {
    int d = dst[e], s = src[e];
    int pos = rowstart[d] + atomicAdd(&cursor[d], 1);
    csr_src[pos] = s;
    csr_w[pos] = dinv[s] * dinv[d];
  }
}

// ---------- GEMM: out[N,128] = xform(in)[N,128] @ W[128,128] (+bias) ----------
// XFORM=1: in := relu(in*scale+shift) applied during LDS staging (fused BN+ReLU).
// OUTH=1: output written as fp16 (for the edge-gather consumer).
template <int XFORM, int OUTH>
__global__ __launch_bounds__(256) void k_gemm(const float* __restrict__ in,
                                              const float* __restrict__ W,
                                              const float* __restrict__ bias,
                                              const float* __restrict__ scale,
                                              const float* __restrict__ shift,
                                              void* __restrict__ outp, int n) {
  __shared__ float Ws[64 * 128];
  __shared__ float hs[64 * 68];
  int tid = threadIdx.x;
  int tx = tid & 15;   // col group: cols tx*4..+3 and 64+tx*4..+3
  int ty = tid >> 4;   // row group: rows ty + 16*i
  int row0 = blockIdx.x * 64;
  float acc[4][8];
#pragma unroll
  for (int i = 0; i < 4; i++)
#pragma unroll
    for (int j = 0; j < 8; j++) acc[i][j] = 0.f;

  for (int k0 = 0; k0 < 128; k0 += 64) {
    __syncthreads();
    // stage W k-half: 64x128 floats
    for (int idx = tid; idx < 64 * 128 / 4; idx += 256) {
      float4 v = ((const float4*)(W + k0 * 128))[idx];
      ((float4*)Ws)[idx] = v;
    }
    // stage h tile: 64 rows x 64 k, padded stride 68
    for (int idx = tid; idx < 64 * 64 / 4; idx += 256) {
      int r = idx >> 4;
      int c4 = idx & 15;
      int row = row0 + r;
      if (row >= n) row = n - 1;
      float4 v = *(const float4*)(in + (size_t)row * 128 + k0 + c4 * 4);
      if (XFORM) {
        float4 sc = *(const float4*)(scale + k0 + c4 * 4);
        float4 sh = *(const float4*)(shift + k0 + c4 * 4);
        v.x = fmaxf(v.x * sc.x + sh.x, 0.f);
        v.y = fmaxf(v.y * sc.y + sh.y, 0.f);
        v.z = fmaxf(v.z * sc.z + sh.z, 0.f);
        v.w = fmaxf(v.w * sc.w + sh.w, 0.f);
      }
      *(float4*)(hs + r * 68 + c4 * 4) = v;
    }
    __syncthreads();
#pragma unroll
    for (int kk = 0; kk < 64; kk += 4) {
      float4 a[4];
#pragma unroll
      for (int i = 0; i < 4; i++) a[i] = *(const float4*)(hs + (ty + 16 * i) * 68 + kk);
#pragma unroll
      for (int kq = 0; kq < 4; kq++) {
        float4 b0 = *(const float4*)(Ws + (kk + kq) * 128 + tx * 4);
        float4 b1 = *(const float4*)(Ws + (kk + kq) * 128 + 64 + tx * 4);
#pragma unroll
        for (int i = 0; i < 4; i++) {
          float aa = ((const float*)&a[i])[kq];
          acc[i][0] += aa * b0.x; acc[i][1] += aa * b0.y;
          acc[i][2] += aa * b0.z; acc[i][3] += aa * b0.w;
          acc[i][4] += aa * b1.x; acc[i][5] += aa * b1.y;
          acc[i][6] += aa * b1.z; acc[i][7] += aa * b1.w;
        }
      }
    }
  }
#pragma unroll
  for (int i = 0; i < 4; i++) {
    int row = row0 + ty + 16 * i;
    if (row < n) {
      if (bias) {
        float4 bb0 = *(const float4*)(bias + tx * 4);
        float4 bb1 = *(const float4*)(bias + 64 + tx * 4);
        acc[i][0] += bb0.x; acc[i][1] += bb0.y; acc[i][2] += bb0.z; acc[i][3] += bb0.w;
        acc[i][4] += bb1.x; acc[i][5] += bb1.y; acc[i][6] += bb1.z; acc[i][7] += bb1.w;
      }
      if (OUTH) {
        __half2* o = (__half2*)outp + (size_t)row * 64;
        o[tx * 2]      = __floats2half2_rn(acc[i][0], acc[i][1]);
        o[tx * 2 + 1]  = __floats2half2_rn(acc[i][2], acc[i][3]);
        o[32 + tx * 2] = __floats2half2_rn(acc[i][4], acc[i][5]);
        o[33 + tx * 2] = __floats2half2_rn(acc[i][6], acc[i][7]);
      } else {
        float* out = (float*)outp;
        *(float4*)(out + (size_t)row * 128 + tx * 4) =
            make_float4(acc[i][0], acc[i][1], acc[i][2], acc[i][3]);
        *(float4*)(out + (size_t)row * 128 + 64 + tx * 4) =
            make_float4(acc[i][4], acc[i][5], acc[i][6], acc[i][7]);
      }
    }
  }
}

// ---------- edge aggregation (fp16 gather, fp32 accumulate) ----------
// out[n] = sum_e w_e*hw[src] + dinv[n]^2*hw[n] + b
__global__ __launch_bounds__(256) void k_agg(const __half2* __restrict__ hw,
                                             const int* __restrict__ rowstart,
                                             const int* __restrict__ csr_src,
                                             const float* __restrict__ csr_w,
                                             const float* __restrict__ dinv,
                                             const float* __restrict__ bias,
                                             float* __restrict__ out, int n) {
  int wave = threadIdx.x >> 6;
  int lane = threadIdx.x & 63;
  int node = blockIdx.x * 4 + wave;
  if (node >= n) return;
  int e0 = rowstart[node], e1 = rowstart[node + 1];
  float ax0 = 0.f, ay0 = 0.f, ax1 = 0.f, ay1 = 0.f;
  float ax2 = 0.f, ay2 = 0.f, ax3 = 0.f, ay3 = 0.f;
  int e = e0;
  for (; e + 3 < e1; e += 4) {
    int s0 = csr_src[e], s1 = csr_src[e + 1], s2 = csr_src[e + 2], s3 = csr_src[e + 3];
    float w0 = csr_w[e], w1 = csr_w[e + 1], w2 = csr_w[e + 2], w3 = csr_w[e + 3];
    float2 f0 = __half22float2(hw[(size_t)s0 * 64 + lane]);
    float2 f1 = __half22float2(hw[(size_t)s1 * 64 + lane]);
    float2 f2 = __half22float2(hw[(size_t)s2 * 64 + lane]);
    float2 f3 = __half22float2(hw[(size_t)s3 * 64 + lane]);
    ax0 += w0 * f0.x; ay0 += w0 * f0.y;
    ax1 += w1 * f1.x; ay1 += w1 * f1.y;
    ax2 += w2 * f2.x; ay2 += w2 * f2.y;
    ax3 += w3 * f3.x; ay3 += w3 * f3.y;
  }
  for (; e < e1; ++e) {
    int s0 = csr_src[e];
    float w0 = csr_w[e];
    float2 f0 = __half22float2(hw[(size_t)s0 * 64 + lane]);
    ax0 += w0 * f0.x; ay0 += w0 * f0.y;
  }
  float ax = (ax0 + ax1) + (ax2 + ax3);
  float ay = (ay0 + ay1) + (ay2 + ay3);
  float dn = dinv[node];
  float sn = dn * dn;
  float2 v = __half22float2(hw[(size_t)node * 64 + lane]);
  float2 bb = *(const float2*)(bias + lane * 2);
  ax += sn * v.x + bb.x;
  ay += sn * v.y + bb.y;
  *(float2*)(out + (size_t)node * 128 + lane * 2) = make_float2(ax, ay);
}

// ---------- column stats (two-stage, deterministic) ----------
__global__ __launch_bounds__(256) void k_colstats(const float* __restrict__ x,
                                                  float* __restrict__ psum,
                                                  float* __restrict__ psq, int n) {
  int c = threadIdx.x & 127;
  int half = threadIdx.x >> 7;
  float s = 0.f, q = 0.f;
  for (int r = blockIdx.x * 2 + half; r < n; r += gridDim.x * 2) {
    float v = x[(size_t)r * 128 + c];
    s += v;
    q += v * v;
  }
  __shared__ float ls[128], lq[128];
  if (half == 1) { ls[c] = s; lq[c] = q; }
  __syncthreads();
  if (half == 0) {
    psum[blockIdx.x * 128 + c] = s + ls[c];
    psq[blockIdx.x * 128 + c] = q + lq[c];
  }
}

__global__ void k_bnfin(const float* __restrict__ psum, const float* __restrict__ psq,
                        const float* __restrict__ g, const float* __restrict__ be,
                        float* __restrict__ scale, float* __restrict__ shift,
                        int nblocks, int n) {
  int c = threadIdx.x;  // 128 threads
  float s = 0.f, q = 0.f;
  for (int b = 0; b < nblocks; b++) {
    s += psum[b * 128 + c];
    q += psq[b * 128 + c];
  }
  float mu = s / (float)n;
  float var = q / (float)n - mu * mu;
  float rs = rsqrtf(var + EPSBN);
  float sc = g[c] * rs;
  scale[c] = sc;
  shift[c] = be[c] - mu * sc;
}

// ---------- BN apply + residual: out += x*scale+shift ----------
__global__ __launch_bounds__(256) void k_bnresid(const float* __restrict__ x,
                                                 const float* __restrict__ scale,
                                                 const float* __restrict__ shift,
                                                 float* __restrict__ out, int n) {
  int idx = blockIdx.x * 256 + threadIdx.x;  // float4 index
  int total = n * 32;
  if (idx >= total) return;
  int c4 = idx & 31;
  float4 v = ((const float4*)x)[idx];
  float4 sc = ((const float4*)scale)[c4];
  float4 sh = ((const float4*)shift)[c4];
  float4 h = ((const float4*)out)[idx];
  float4 o;
  o.x = v.x * sc.x + sh.x + h.x;
  o.y = v.y * sc.y + sh.y + h.y;
  o.z = v.z * sc.z + sh.z + h.z;
  o.w = v.w * sc.w + sh.w + h.w;
  ((float4*)out)[idx] = o;
}

// ---------- pooling: batch is SORTED -> segment reduction, flush at boundaries ----------
#define PCHUNK 128
__global__ __launch_bounds__(128) void k_pool(const float* __restrict__ h,
                                              const int* __restrict__ batch,
                                              float* __restrict__ sums,
                                              unsigned* __restrict__ maxenc,
                                              int* __restrict__ cnt, int n) {
  int c = threadIdx.x;  // column 0..127
  int start = blockIdx.x * PCHUNK;
  if (start >= n) return;
  int end = start + PCHUNK;
  if (end > n) end = n;
  int cur = batch[start];
  float s = 0.f, mx = -FLT_MAX;
  int runlen = 0;
  for (int i = start; i < end; ++i) {
    int b = batch[i];
    if (b != cur) {
      atomicAdd(&sums[cur * 128 + c], s);
      atomicMax(&maxenc[cur * 128 + c], enc_f(mx));
      if (c == 0) atomicAdd(&cnt[cur], runlen);
      s = 0.f; mx = -FLT_MAX; runlen = 0; cur = b;
    }
    float v = h[(size_t)i * 128 + c];
    s += v;
    mx = fmaxf(mx, v);
    runlen++;
  }
  atomicAdd(&sums[cur * 128 + c], s);
  atomicMax(&maxenc[cur * 128 + c], enc_f(mx));
  if (c == 0) atomicAdd(&cnt[cur], runlen);
}

// ---------- readout MLP: [mean|max|sum](384) -> 256 -> 128 -> 1 ----------
__global__ __launch_bounds__(256) void k_readout(const float* __restrict__ sums,
                                                 const unsigned* __restrict__ maxenc,
                                                 const int* __restrict__ cnt,
                                                 const float* __restrict__ Wa,
                                                 const float* __restrict__ ba,
                                                 const float* __restrict__ Wb,
                                                 const float* __restrict__ bb,
                                                 const float* __restrict__ Wc,
                                                 const float* __restrict__ bc,
                                                 float* __restrict__ out) {
  int g = blockIdx.x;
  int t = threadIdx.x;
  __shared__ float z[384];
  __shared__ float za[256];
  __shared__ float zb[128];
  float c = (float)(cnt[g] > 1 ? cnt[g] : 1);
  if (t < 128) {
    float s = sums[g * 128 + t];
    z[t] = s / c;
    z[128 + t] = dec_f(maxenc[g * 128 + t]);
    z[256 + t] = s;
  }
  __syncthreads();
  float accA = ba[t];
  for (int k = 0; k < 384; k++) accA += z[k] * Wa[k * 256 + t];
  za[t] = fmaxf(accA, 0.f);
  __syncthreads();
  if (t < 128) {
    float accB = bb[t];
    for (int k = 0; k < 256; k++) accB += za[k] * Wb[k * 128 + t];
    zb[t] = fmaxf(accB, 0.f);
  }
  __syncthreads();
  if (t < 64) {
    float p = zb[t] * Wc[t] + zb[t + 64] * Wc[t + 64];
    for (int off = 32; off > 0; off >>= 1) p += __shfl_down(p, off);
    if (t == 0) out[g] = p + bc[0];
  }
}

extern "C" void kernel_launch(void* const* d_in, const int* in_sizes, int n_in,
                              void* d_out, int out_size, void* d_ws, size_t ws_size,
                              hipStream_t stream) {
  const float* x   = (const float*)d_in[0];
  const int* edge  = (const int*)d_in[1];
  const int* batch = (const int*)d_in[2];
  const float* Wp  = (const float*)d_in[3];
  const float* bp  = (const float*)d_in[4];
  const float* W1  = (const float*)d_in[5];
  const float* b1  = (const float*)d_in[6];
  const float* g1  = (const float*)d_in[7];
  const float* be1 = (const float*)d_in[8];
  const float* W2  = (const float*)d_in[9];
  const float* b2  = (const float*)d_in[10];
  const float* g2  = (const float*)d_in[11];
  const float* be2 = (const float*)d_in[12];
  const float* Wa  = (const float*)d_in[13];
  const float* ba  = (const float*)d_in[14];
  const float* Wb  = (const float*)d_in[15];
  const float* bbp = (const float*)d_in[16];
  const float* Wc  = (const float*)d_in[17];
  const float* bc  = (const float*)d_in[18];
  float* out = (float*)d_out;

  const int N = in_sizes[0] / 128;
  const int E = in_sizes[1] / 2;
  const int* esrc = edge;
  const int* edst = edge + E;

  // workspace carve
  char* p = (char*)d_ws;
  auto carve = [&](size_t bytes) {
    char* r = p;
    p += (bytes + 255) & ~(size_t)255;
    return (void*)r;
  };
  float* h   = (float*)carve((size_t)N * 128 * 4);
  __half* t1h = (__half*)carve((size_t)N * 128 * 2);  // fp16 hw buffer
  float* t2  = (float*)carve((size_t)N * 128 * 4);
  int* csr_src = (int*)carve((size_t)E * 4);
  float* csr_w = (float*)carve((size_t)E * 4);
  int* deg     = (int*)carve((size_t)N * 4);
  float* dinv  = (float*)carve((size_t)N * 4);
  int* rowstart = (int*)carve((size_t)(N + 1) * 4);
  int* cursor   = (int*)carve((size_t)N * 4);
  int* bsum     = (int*)carve(512 * 4);
  float* psum   = (float*)carve(256 * 128 * 4);
  float* psq    = (float*)carve(256 * 128 * 4);
  float* scale  = (float*)carve(128 * 4);
  float* shift  = (float*)carve(128 * 4);
  float* pools  = (float*)carve((size_t)NGRAPH * 128 * 4);
  unsigned* poolm = (unsigned*)carve((size_t)NGRAPH * 128 * 4);
  int* poolc      = (int*)carve(NGRAPH * 4);

  const int NB = (N + 255) / 256;  // scan blocks

  hipMemsetAsync(deg, 0, (size_t)N * 4, stream);
  hipMemsetAsync(cursor, 0, (size_t)N * 4, stream);
  hipMemsetAsync(pools, 0, (size_t)NGRAPH * 128 * 4, stream);
  hipMemsetAsync(poolm, 0, (size_t)NGRAPH * 128 * 4, stream);
  hipMemsetAsync(poolc, 0, (size_t)NGRAPH * 4, stream);

  k_deg<<<(E + 255) / 256, 256, 0, stream>>>(edst, deg, E);
  k_dinv<<<NB, 256, 0, stream>>>(deg, dinv, N);
  k_scanA<<<NB, 256, 0, stream>>>(deg, rowstart, bsum, N);
  k_scanB<<<1, 512, 0, stream>>>(bsum, NB);
  k_scanC<<<NB, 256, 0, stream>>>(rowstart, bsum, N, E);
  k_fill<<<(E + 255) / 256, 256, 0, stream>>>(esrc, edst, dinv, rowstart, cursor,
                                              csr_src, csr_w, E);

  const int GB = (N + 63) / 64;    // gemm blocks
  const int AB = (N + 3) / 4;      // agg blocks
  const int EB = (N * 32 + 255) / 256;  // elementwise blocks (float4)
  const int PB = (N + PCHUNK - 1) / PCHUNK;

  k_gemm<0, 0><<<GB, 256, 0, stream>>>(x, Wp, bp, nullptr, nullptr, h, N);

  for (int l = 0; l < 8; l++) {
    // hw1 = h @ W1 (fp16 out); t2 = agg(hw1) + b1
    k_gemm<0, 1><<<GB, 256, 0, stream>>>(h, W1 + (size_t)l * 128 * 128, nullptr, nullptr, nullptr, t1h, N);
    k_agg<<<AB, 256, 0, stream>>>((const __half2*)t1h, rowstart, csr_src, csr_w, dinv, b1 + l * 128, t2, N);
    k_colstats<<<256, 256, 0, stream>>>(t2, psum, psq, N);
    k_bnfin<<<1, 128, 0, stream>>>(psum, psq, g1 + l * 128, be1 + l * 128, scale, shift, 256, N);
    // hw2 = relu(bn1(t2)) @ W2 (BN+ReLU fused into staging, fp16 out)
    k_gemm<1, 1><<<GB, 256, 0, stream>>>(t2, W2 + (size_t)l * 128 * 128, nullptr, scale, shift, t1h, N);
    k_agg<<<AB, 256, 0, stream>>>((const __half2*)t1h, rowstart, csr_src, csr_w, dinv, b2 + l * 128, t2, N);
    k_colstats<<<256, 256, 0, stream>>>(t2, psum, psq, N);
    k_bnfin<<<1, 128, 0, stream>>>(psum, psq, g2 + l * 128, be2 + l * 128, scale, shift, 256, N);
    // h += bn2(t2)
    k_bnresid<<<EB, 256, 0, stream>>>(t2, scale, shift, h, N);
  }

  k_pool<<<PB, 128, 0, stream>>>(h, batch, pools, poolm, poolc, N);
  k_readout<<<NGRAPH, 256, 0, stream>>>(pools, poolm, poolc, Wa, ba, Wb, bbp, Wc, bc, out);
}

// Round 4
// 3604.013 us; speedup vs baseline: 1.7603x; 1.2959x over previous
//
#include <hip/hip_runtime.h>
#include <hip/hip_fp16.h>
#include <math.h>
#include <float.h>

#define HDIM 128
#define NGRAPH 256
#define EPSBN 1e-5f

typedef _Float16 f16x8 __attribute__((ext_vector_type(8)));
typedef _Float16 f16x4 __attribute__((ext_vector_type(4)));
typedef float f32x4 __attribute__((ext_vector_type(4)));

// ---------- float<->ordered-uint encoding for atomic max ----------
__device__ inline unsigned enc_f(float v) {
  unsigned u = __float_as_uint(v);
  return (u & 0x80000000u) ? ~u : (u | 0x80000000u);
}
__device__ inline float dec_f(unsigned e) {
  return __uint_as_float((e & 0x80000000u) ? (e ^ 0x80000000u) : ~e);
}

// ---------- degree / dinv ----------
__global__ void k_deg(const int* __restrict__ dst, int* __restrict__ deg, int E) {
  int i = blockIdx.x * blockDim.x + threadIdx.x;
  if (i < E) atomicAdd(&deg[dst[i]], 1);
}

__global__ void k_dinv(const int* __restrict__ deg, float* __restrict__ dinv, int n) {
  int i = blockIdx.x * blockDim.x + threadIdx.x;
  if (i < n) dinv[i] = rsqrtf((float)deg[i] + 1.0f);
}

// ---------- 2-level exclusive scan of deg -> rowstart ----------
__global__ void k_scanA(const int* __restrict__ deg, int* __restrict__ rowstart,
                        int* __restrict__ bsum, int n) {
  __shared__ int s[256];
  int t = threadIdx.x, i = blockIdx.x * 256 + t;
  int v = (i < n) ? deg[i] : 0;
  s[t] = v;
  __syncthreads();
  for (int off = 1; off < 256; off <<= 1) {
    int x = (t >= off) ? s[t - off] : 0;
    __syncthreads();
    s[t] += x;
    __syncthreads();
  }
  if (i < n) rowstart[i] = s[t] - v;  // exclusive
  if (t == 255) bsum[blockIdx.x] = s[255];
}

__global__ void k_scanB(int* __restrict__ bsum, int nb) {
  __shared__ int s[512];
  int t = threadIdx.x;
  int v = (t < nb) ? bsum[t] : 0;
  s[t] = v;
  __syncthreads();
  for (int off = 1; off < 512; off <<= 1) {
    int x = (t >= off) ? s[t - off] : 0;
    __syncthreads();
    s[t] += x;
    __syncthreads();
  }
  if (t < nb) bsum[t] = s[t] - v;  // exclusive
}

__global__ void k_scanC(int* __restrict__ rowstart, const int* __restrict__ bsum,
                        int n, int E) {
  int i = blockIdx.x * 256 + threadIdx.x;
  if (i < n) rowstart[i] += bsum[blockIdx.x];
  if (i == 0) rowstart[n] = E;
}

// combined {src, weight} 8B scatter (half the random-write lines vs two 4B arrays)
__global__ void k_fill(const int* __restrict__ src, const int* __restrict__ dst,
                       const float* __restrict__ dinv, const int* __restrict__ rowstart,
                       int* __restrict__ cursor, int2* __restrict__ csr_sw, int E) {
  int e = blockIdx.x * blockDim.x + threadIdx.x;
  if (e < E) {
    int d = dst[e], s = src[e];
    int pos = rowstart[d] + atomicAdd(&cursor[d], 1);
    csr_sw[pos] = make_int2(s, __float_as_int(dinv[s] * dinv[d]));
  }
}

// ---------- weight prep: fp32 [k][col] -> fp16 [col][k], 16 matrices ----------
__global__ __launch_bounds__(256) void k_wprep(const float* __restrict__ W1,
                                               const float* __restrict__ W2,
                                               _Float16* __restrict__ wt) {
  int m = blockIdx.x;           // 0..15: layer l = m>>1, which = m&1
  const float* Wsrc = ((m & 1) ? W2 : W1) + (size_t)(m >> 1) * 16384;
  _Float16* Wdst = wt + (size_t)m * 16384;
  __shared__ _Float16 lds[128 * 132];
  int t = threadIdx.x;
  const float4* W4 = (const float4*)Wsrc;
  for (int it = 0; it < 16; ++it) {
    int idx = t + it * 256;     // 4096 float4s
    int k = idx >> 5, c4 = idx & 31;
    float4 v = W4[idx];
    lds[(c4 * 4 + 0) * 132 + k] = (_Float16)v.x;
    lds[(c4 * 4 + 1) * 132 + k] = (_Float16)v.y;
    lds[(c4 * 4 + 2) * 132 + k] = (_Float16)v.z;
    lds[(c4 * 4 + 3) * 132 + k] = (_Float16)v.w;
  }
  __syncthreads();
  for (int it = 0; it < 16; ++it) {
    int idx = t + it * 256;     // 4096 f16x4s
    int col = idx >> 5, k4 = idx & 31;
    f16x4 o;
    o[0] = lds[col * 132 + k4 * 4 + 0];
    o[1] = lds[col * 132 + k4 * 4 + 1];
    o[2] = lds[col * 132 + k4 * 4 + 2];
    o[3] = lds[col * 132 + k4 * 4 + 3];
    *(f16x4*)(Wdst + col * 128 + k4 * 4) = o;
  }
}

// ---------- fp32 VALU GEMM (projection only): out = in @ W + b ----------
__global__ __launch_bounds__(256) void k_gemmf(const float* __restrict__ in,
                                               const float* __restrict__ W,
                                               const float* __restrict__ bias,
                                               float* __restrict__ out, int n) {
  __shared__ float Ws[64 * 128];
  __shared__ float hs[64 * 68];
  int tid = threadIdx.x;
  int tx = tid & 15;
  int ty = tid >> 4;
  int row0 = blockIdx.x * 64;
  float acc[4][8];
#pragma unroll
  for (int i = 0; i < 4; i++)
#pragma unroll
    for (int j = 0; j < 8; j++) acc[i][j] = 0.f;

  for (int k0 = 0; k0 < 128; k0 += 64) {
    __syncthreads();
    for (int idx = tid; idx < 64 * 128 / 4; idx += 256) {
      float4 v = ((const float4*)(W + k0 * 128))[idx];
      ((float4*)Ws)[idx] = v;
    }
    for (int idx = tid; idx < 64 * 64 / 4; idx += 256) {
      int r = idx >> 4;
      int c4 = idx & 15;
      int row = row0 + r;
      if (row >= n) row = n - 1;
      float4 v = *(const float4*)(in + (size_t)row * 128 + k0 + c4 * 4);
      *(float4*)(hs + r * 68 + c4 * 4) = v;
    }
    __syncthreads();
#pragma unroll
    for (int kk = 0; kk < 64; kk += 4) {
      float4 a[4];
#pragma unroll
      for (int i = 0; i < 4; i++) a[i] = *(const float4*)(hs + (ty + 16 * i) * 68 + kk);
#pragma unroll
      for (int kq = 0; kq < 4; kq++) {
        float4 b0 = *(const float4*)(Ws + (kk + kq) * 128 + tx * 4);
        float4 b1 = *(const float4*)(Ws + (kk + kq) * 128 + 64 + tx * 4);
#pragma unroll
        for (int i = 0; i < 4; i++) {
          float aa = ((const float*)&a[i])[kq];
          acc[i][0] += aa * b0.x; acc[i][1] += aa * b0.y;
          acc[i][2] += aa * b0.z; acc[i][3] += aa * b0.w;
          acc[i][4] += aa * b1.x; acc[i][5] += aa * b1.y;
          acc[i][6] += aa * b1.z; acc[i][7] += aa * b1.w;
        }
      }
    }
  }
#pragma unroll
  for (int i = 0; i < 4; i++) {
    int row = row0 + ty + 16 * i;
    if (row < n) {
      float4 bb0 = *(const float4*)(bias + tx * 4);
      float4 bb1 = *(const float4*)(bias + 64 + tx * 4);
      *(float4*)(out + (size_t)row * 128 + tx * 4) =
          make_float4(acc[i][0] + bb0.x, acc[i][1] + bb0.y, acc[i][2] + bb0.z, acc[i][3] + bb0.w);
      *(float4*)(out + (size_t)row * 128 + 64 + tx * 4) =
          make_float4(acc[i][4] + bb1.x, acc[i][5] + bb1.y, acc[i][6] + bb1.z, acc[i][7] + bb1.w);
    }
  }
}

// ---------- MFMA f16 GEMM: outh[N,128] = xform(in)[N,128] @ W (fp16 out) ----------
// XFORM=1: in := relu(in*scale+shift) during staging. wt = fp16 W^T [col][k].
// BM=64, 4 waves; wave rt handles rows rt*16..+16, all 8 col-tiles.
// LDS: As 64x128 f16 (16KB) + Bs 128x128 f16 (32KB), XOR-swizzled (T2).
template <int XFORM>
__global__ __launch_bounds__(256) void k_gemmh(const float* __restrict__ in,
                                               const _Float16* __restrict__ wt,
                                               const float* __restrict__ scale,
                                               const float* __restrict__ shift,
                                               _Float16* __restrict__ outh, int n) {
  __shared__ _Float16 As[64 * 128];
  __shared__ _Float16 Bs[128 * 128];
  char* Ap = (char*)As;
  char* Bp = (char*)Bs;
  int tid = threadIdx.x;
  int lane = tid & 63;
  int rt = tid >> 6;  // wave id = row tile
  int row0 = blockIdx.x * 64;

  // stage A: 64x128 fp32 -> f16, optional BN+ReLU. 2048 float4s.
  for (int it = 0; it < 8; ++it) {
    int idx = tid + it * 256;
    int r = idx >> 5, c4 = idx & 31;
    int row = row0 + r;
    if (row >= n) row = n - 1;
    float4 v = *(const float4*)(in + (size_t)row * 128 + c4 * 4);
    if (XFORM) {
      float4 sc = *(const float4*)(scale + c4 * 4);
      float4 sh = *(const float4*)(shift + c4 * 4);
      v.x = fmaxf(v.x * sc.x + sh.x, 0.f);
      v.y = fmaxf(v.y * sc.y + sh.y, 0.f);
      v.z = fmaxf(v.z * sc.z + sh.z, 0.f);
      v.w = fmaxf(v.w * sc.w + sh.w, 0.f);
    }
    f16x4 hv;
    hv[0] = (_Float16)v.x; hv[1] = (_Float16)v.y;
    hv[2] = (_Float16)v.z; hv[3] = (_Float16)v.w;
    *(f16x4*)(Ap + ((r * 256 + c4 * 8) ^ ((r & 7) << 4))) = hv;
  }
  // stage B: wt fp16 [col][k], 2048 f16x8s (16B each)
  for (int it = 0; it < 8; ++it) {
    int idx = tid + it * 256;
    int col = idx >> 4, k8 = idx & 15;
    f16x8 v = *(const f16x8*)(wt + col * 128 + k8 * 8);
    *(f16x8*)(Bp + ((col * 256 + k8 * 16) ^ ((col & 7) << 4))) = v;
  }
  __syncthreads();

  f32x4 acc[8];
#pragma unroll
  for (int ct = 0; ct < 8; ++ct) acc[ct] = (f32x4){0.f, 0.f, 0.f, 0.f};

  int arow = rt * 16 + (lane & 15);
  int kc = (lane >> 4) * 16;  // byte offset of lane's k-chunk
#pragma unroll
  for (int ks = 0; ks < 4; ++ks) {
    int kb = ks * 64;  // 32 k * 2B
    f16x8 a = *(f16x8*)(Ap + ((arow * 256 + kb + kc) ^ ((arow & 7) << 4)));
#pragma unroll
    for (int ct = 0; ct < 8; ++ct) {
      int bcol = ct * 16 + (lane & 15);
      f16x8 b = *(f16x8*)(Bp + ((bcol * 256 + kb + kc) ^ ((bcol & 7) << 4)));
      acc[ct] = __builtin_amdgcn_mfma_f32_16x16x32_f16(a, b, acc[ct], 0, 0, 0);
    }
  }

  // epilogue: C/D layout col=lane&15, row=(lane>>4)*4+reg (m89-verified)
  int orow0 = row0 + rt * 16 + (lane >> 4) * 4;
#pragma unroll
  for (int ct = 0; ct < 8; ++ct) {
    int col = ct * 16 + (lane & 15);
#pragma unroll
    for (int r = 0; r < 4; ++r) {
      int row = orow0 + r;
      if (row < n) outh[(size_t)row * 128 + col] = (_Float16)acc[ct][r];
    }
  }
}

// ---------- edge aggregation + fused BN stats ----------
// 16-lane group per node: lane i covers cols i*8..+8 (16B f16x8 loads).
// out = sum_e w*hw[src] + dinv^2*hw[node] + bias;  psum/psq += column stats.
__global__ __launch_bounds__(256) void k_agg(const _Float16* __restrict__ hw,
                                             const int* __restrict__ rowstart,
                                             const int2* __restrict__ csr_sw,
                                             const float* __restrict__ dinv,
                                             const float* __restrict__ bias,
                                             float* __restrict__ out,
                                             float* __restrict__ psum,
                                             float* __restrict__ psq, int n) {
  int t = threadIdx.x;
  int g = t >> 4;    // group 0..15
  int i = t & 15;    // lane in group
  int node = blockIdx.x * 16 + g;
  int c0 = i * 8;
  float a0[8], a1[8];
#pragma unroll
  for (int j = 0; j < 8; ++j) { a0[j] = 0.f; a1[j] = 0.f; }

  if (node < n) {
    int e0 = rowstart[node], e1 = rowstart[node + 1];
    int e = e0;
    for (; e + 1 < e1; e += 2) {
      int2 s0 = csr_sw[e];
      int2 s1 = csr_sw[e + 1];
      float w0 = __int_as_float(s0.y);
      float w1 = __int_as_float(s1.y);
      f16x8 v0 = *(const f16x8*)(hw + (size_t)s0.x * 128 + c0);
      f16x8 v1 = *(const f16x8*)(hw + (size_t)s1.x * 128 + c0);
#pragma unroll
      for (int j = 0; j < 8; ++j) {
        a0[j] += w0 * (float)v0[j];
        a1[j] += w1 * (float)v1[j];
      }
    }
    if (e < e1) {
      int2 s0 = csr_sw[e];
      float w0 = __int_as_float(s0.y);
      f16x8 v0 = *(const f16x8*)(hw + (size_t)s0.x * 128 + c0);
#pragma unroll
      for (int j = 0; j < 8; ++j) a0[j] += w0 * (float)v0[j];
    }
    float dn = dinv[node];
    float sn = dn * dn;
    f16x8 v = *(const f16x8*)(hw + (size_t)node * 128 + c0);
    float4 b0 = *(const float4*)(bias + c0);
    float4 b1 = *(const float4*)(bias + c0 + 4);
#pragma unroll
    for (int j = 0; j < 8; ++j) a0[j] += a1[j] + sn * (float)v[j];
    a0[0] += b0.x; a0[1] += b0.y; a0[2] += b0.z; a0[3] += b0.w;
    a0[4] += b1.x; a0[5] += b1.y; a0[6] += b1.z; a0[7] += b1.w;
    *(float4*)(out + (size_t)node * 128 + c0) = make_float4(a0[0], a0[1], a0[2], a0[3]);
    *(float4*)(out + (size_t)node * 128 + c0 + 4) = make_float4(a0[4], a0[5], a0[6], a0[7]);
  }

  // fused column stats: block-reduce 16 node-rows, then one atomic per col
  __shared__ float ls[16][128];
  __shared__ float lq[16][128];
#pragma unroll
  for (int j = 0; j < 8; ++j) {
    float v = (node < n) ? a0[j] : 0.f;
    ls[g][c0 + j] = v;
    lq[g][c0 + j] = v * v;
  }
  __syncthreads();
  if (t < 128) {
    float s = 0.f, q = 0.f;
#pragma unroll
    for (int gg = 0; gg < 16; ++gg) { s += ls[gg][t]; q += lq[gg][t]; }
    atomicAdd(&psum[t], s);
    atomicAdd(&psq[t], q);
  }
}

// ---------- BN finalize: scale/shift from psum/psq; re-zero accumulators ----------
__global__ void k_bnfin(float* __restrict__ psum, float* __restrict__ psq,
                        const float* __restrict__ g, const float* __restrict__ be,
                        float* __restrict__ scale, float* __restrict__ shift, int n) {
  int c = threadIdx.x;  // 128
  float s = psum[c], q = psq[c];
  float mu = s / (float)n;
  float var = q / (float)n - mu * mu;
  float rs = rsqrtf(var + EPSBN);
  float sc = g[c] * rs;
  scale[c] = sc;
  shift[c] = be[c] - mu * sc;
  psum[c] = 0.f;
  psq[c] = 0.f;
}

// ---------- BN apply + residual: out += x*scale+shift ----------
__global__ __launch_bounds__(256) void k_bnresid(const float* __restrict__ x,
                                                 const float* __restrict__ scale,
                                                 const float* __restrict__ shift,
                                                 float* __restrict__ out, int n) {
  int idx = blockIdx.x * 256 + threadIdx.x;  // float4 index
  int total = n * 32;
  if (idx >= total) return;
  int c4 = idx & 31;
  float4 v = ((const float4*)x)[idx];
  float4 sc = ((const float4*)scale)[c4];
  float4 sh = ((const float4*)shift)[c4];
  float4 h = ((const float4*)out)[idx];
  ((float4*)out)[idx] = make_float4(v.x * sc.x + sh.x + h.x, v.y * sc.y + sh.y + h.y,
                                    v.z * sc.z + sh.z + h.z, v.w * sc.w + sh.w + h.w);
}

// ---------- pooling: batch sorted -> segment reduction ----------
#define PCHUNK 128
__global__ __launch_bounds__(128) void k_pool(const float* __restrict__ h,
                                              const int* __restrict__ batch,
                                              float* __restrict__ sums,
                                              unsigned* __restrict__ maxenc,
                                              int* __restrict__ cnt, int n) {
  int c = threadIdx.x;
  int start = blockIdx.x * PCHUNK;
  if (start >= n) return;
  int end = start + PCHUNK;
  if (end > n) end = n;
  int cur = batch[start];
  float s = 0.f, mx = -FLT_MAX;
  int runlen = 0;
  for (int i = start; i < end; ++i) {
    int b = batch[i];
    if (b != cur) {
      atomicAdd(&sums[cur * 128 + c], s);
      atomicMax(&maxenc[cur * 128 + c], enc_f(mx));
      if (c == 0) atomicAdd(&cnt[cur], runlen);
      s = 0.f; mx = -FLT_MAX; runlen = 0; cur = b;
    }
    float v = h[(size_t)i * 128 + c];
    s += v;
    mx = fmaxf(mx, v);
    runlen++;
  }
  atomicAdd(&sums[cur * 128 + c], s);
  atomicMax(&maxenc[cur * 128 + c], enc_f(mx));
  if (c == 0) atomicAdd(&cnt[cur], runlen);
}

// ---------- readout MLP ----------
__global__ __launch_bounds__(256) void k_readout(const float* __restrict__ sums,
                                                 const unsigned* __restrict__ maxenc,
                                                 const int* __restrict__ cnt,
                                                 const float* __restrict__ Wa,
                                                 const float* __restrict__ ba,
                                                 const float* __restrict__ Wb,
                                                 const float* __restrict__ bb,
                                                 const float* __restrict__ Wc,
                                                 const float* __restrict__ bc,
                                                 float* __restrict__ out) {
  int g = blockIdx.x;
  int t = threadIdx.x;
  __shared__ float z[384];
  __shared__ float za[256];
  __shared__ float zb[128];
  float c = (float)(cnt[g] > 1 ? cnt[g] : 1);
  if (t < 128) {
    float s = sums[g * 128 + t];
    z[t] = s / c;
    z[128 + t] = dec_f(maxenc[g * 128 + t]);
    z[256 + t] = s;
  }
  __syncthreads();
  float accA = ba[t];
  for (int k = 0; k < 384; k++) accA += z[k] * Wa[k * 256 + t];
  za[t] = fmaxf(accA, 0.f);
  __syncthreads();
  if (t < 128) {
    float accB = bb[t];
    for (int k = 0; k < 256; k++) accB += za[k] * Wb[k * 128 + t];
    zb[t] = fmaxf(accB, 0.f);
  }
  __syncthreads();
  if (t < 64) {
    float p = zb[t] * Wc[t] + zb[t + 64] * Wc[t + 64];
    for (int off = 32; off > 0; off >>= 1) p += __shfl_down(p, off);
    if (t == 0) out[g] = p + bc[0];
  }
}

extern "C" void kernel_launch(void* const* d_in, const int* in_sizes, int n_in,
                              void* d_out, int out_size, void* d_ws, size_t ws_size,
                              hipStream_t stream) {
  const float* x   = (const float*)d_in[0];
  const int* edge  = (const int*)d_in[1];
  const int* batch = (const int*)d_in[2];
  const float* Wp  = (const float*)d_in[3];
  const float* bp  = (const float*)d_in[4];
  const float* W1  = (const float*)d_in[5];
  const float* b1  = (const float*)d_in[6];
  const float* g1  = (const float*)d_in[7];
  const float* be1 = (const float*)d_in[8];
  const float* W2  = (const float*)d_in[9];
  const float* b2  = (const float*)d_in[10];
  const float* g2  = (const float*)d_in[11];
  const float* be2 = (const float*)d_in[12];
  const float* Wa  = (const float*)d_in[13];
  const float* ba  = (const float*)d_in[14];
  const float* Wb  = (const float*)d_in[15];
  const float* bbp = (const float*)d_in[16];
  const float* Wc  = (const float*)d_in[17];
  const float* bc  = (const float*)d_in[18];
  float* out = (float*)d_out;

  const int N = in_sizes[0] / 128;
  const int E = in_sizes[1] / 2;
  const int* esrc = edge;
  const int* edst = edge + E;

  char* p = (char*)d_ws;
  auto carve = [&](size_t bytes) {
    char* r = p;
    p += (bytes + 255) & ~(size_t)255;
    return (void*)r;
  };
  float* h    = (float*)carve((size_t)N * 128 * 4);
  _Float16* t1h = (_Float16*)carve((size_t)N * 128 * 2);
  float* t2   = (float*)carve((size_t)N * 128 * 4);
  int2* csr_sw = (int2*)carve((size_t)E * 8);
  int* deg     = (int*)carve((size_t)N * 4);
  float* dinv  = (float*)carve((size_t)N * 4);
  int* rowstart = (int*)carve((size_t)(N + 1) * 4);
  int* cursor   = (int*)carve((size_t)N * 4);
  int* bsum     = (int*)carve(512 * 4);
  float* psum   = (float*)carve(256 * 4);   // psum[128] + psq[128]
  float* psq    = psum + 128;
  float* scale  = (float*)carve(128 * 4);
  float* shift  = (float*)carve(128 * 4);
  float* pools  = (float*)carve((size_t)NGRAPH * 128 * 4);
  unsigned* poolm = (unsigned*)carve((size_t)NGRAPH * 128 * 4);
  int* poolc      = (int*)carve(NGRAPH * 4);
  _Float16* wt16  = (_Float16*)carve((size_t)16 * 128 * 128 * 2);

  const int NB = (N + 255) / 256;

  hipMemsetAsync(deg, 0, (size_t)N * 4, stream);
  hipMemsetAsync(cursor, 0, (size_t)N * 4, stream);
  hipMemsetAsync(psum, 0, 256 * 4, stream);
  hipMemsetAsync(pools, 0, (size_t)NGRAPH * 128 * 4, stream);
  hipMemsetAsync(poolm, 0, (size_t)NGRAPH * 128 * 4, stream);
  hipMemsetAsync(poolc, 0, (size_t)NGRAPH * 4, stream);

  k_deg<<<(E + 255) / 256, 256, 0, stream>>>(edst, deg, E);
  k_dinv<<<NB, 256, 0, stream>>>(deg, dinv, N);
  k_scanA<<<NB, 256, 0, stream>>>(deg, rowstart, bsum, N);
  k_scanB<<<1, 512, 0, stream>>>(bsum, NB);
  k_scanC<<<NB, 256, 0, stream>>>(rowstart, bsum, N, E);
  k_fill<<<(E + 255) / 256, 256, 0, stream>>>(esrc, edst, dinv, rowstart, cursor, csr_sw, E);
  k_wprep<<<16, 256, 0, stream>>>(W1, W2, wt16);

  const int GB = (N + 63) / 64;
  const int AB = (N + 15) / 16;
  const int EB = (N * 32 + 255) / 256;
  const int PB = (N + PCHUNK - 1) / PCHUNK;

  k_gemmf<<<GB, 256, 0, stream>>>(x, Wp, bp, h, N);

  for (int l = 0; l < 8; l++) {
    const _Float16* w1t = wt16 + (size_t)(l * 2) * 16384;
    const _Float16* w2t = wt16 + (size_t)(l * 2 + 1) * 16384;
    // hw1 = h @ W1 (f16 MFMA); t2 = agg(hw1)+b1 (+stats)
    k_gemmh<0><<<GB, 256, 0, stream>>>(h, w1t, nullptr, nullptr, t1h, N);
    k_agg<<<AB, 256, 0, stream>>>(t1h, rowstart, csr_sw, dinv, b1 + l * 128, t2, psum, psq, N);
    k_bnfin<<<1, 128, 0, stream>>>(psum, psq, g1 + l * 128, be1 + l * 128, scale, shift, N);
    // hw2 = relu(bn1(t2)) @ W2 (fused BN+ReLU staging); t2 = agg(hw2)+b2 (+stats)
    k_gemmh<1><<<GB, 256, 0, stream>>>(t2, w2t, scale, shift, t1h, N);
    k_agg<<<AB, 256, 0, stream>>>(t1h, rowstart, csr_sw, dinv, b2 + l * 128, t2, psum, psq, N);
    k_bnfin<<<1, 128, 0, stream>>>(psum, psq, g2 + l * 128, be2 + l * 128, scale, shift, N);
    // h += bn2(t2)
    k_bnresid<<<EB, 256, 0, stream>>>(t2, scale, shift, h, N);
  }

  k_pool<<<PB, 128, 0, stream>>>(h, batch, pools, poolm, poolc, N);
  k_readout<<<NGRAPH, 256, 0, stream>>>(pools, poolm, poolc, Wa, ba, Wb, bbp, Wc, bc, out);
}

// Round 5
// 2169.429 us; speedup vs baseline: 2.9243x; 1.6613x over previous
//
#include <hip/hip_runtime.h>
#include <hip/hip_fp16.h>
#include <math.h>
#include <float.h>

#define HDIM 128
#define NGRAPH 256
#define EPSBN 1e-5f
#define PS_REP 32

typedef _Float16 f16x8 __attribute__((ext_vector_type(8)));
typedef _Float16 f16x4 __attribute__((ext_vector_type(4)));
typedef float f32x4 __attribute__((ext_vector_type(4)));

// ---------- float<->ordered-uint encoding for atomic max ----------
__device__ inline unsigned enc_f(float v) {
  unsigned u = __float_as_uint(v);
  return (u & 0x80000000u) ? ~u : (u | 0x80000000u);
}
__device__ inline float dec_f(unsigned e) {
  return __uint_as_float((e & 0x80000000u) ? (e ^ 0x80000000u) : ~e);
}

// ---------- degree / dinv ----------
__global__ void k_deg(const int* __restrict__ dst, int* __restrict__ deg, int E) {
  int i = blockIdx.x * blockDim.x + threadIdx.x;
  if (i < E) atomicAdd(&deg[dst[i]], 1);
}

__global__ void k_dinv(const int* __restrict__ deg, float* __restrict__ dinv, int n) {
  int i = blockIdx.x * blockDim.x + threadIdx.x;
  if (i < n) dinv[i] = rsqrtf((float)deg[i] + 1.0f);
}

// ---------- 2-level exclusive scan of deg -> rowstart ----------
__global__ void k_scanA(const int* __restrict__ deg, int* __restrict__ rowstart,
                        int* __restrict__ bsum, int n) {
  __shared__ int s[256];
  int t = threadIdx.x, i = blockIdx.x * 256 + t;
  int v = (i < n) ? deg[i] : 0;
  s[t] = v;
  __syncthreads();
  for (int off = 1; off < 256; off <<= 1) {
    int x = (t >= off) ? s[t - off] : 0;
    __syncthreads();
    s[t] += x;
    __syncthreads();
  }
  if (i < n) rowstart[i] = s[t] - v;  // exclusive
  if (t == 255) bsum[blockIdx.x] = s[255];
}

__global__ void k_scanB(int* __restrict__ bsum, int nb) {
  __shared__ int s[512];
  int t = threadIdx.x;
  int v = (t < nb) ? bsum[t] : 0;
  s[t] = v;
  __syncthreads();
  for (int off = 1; off < 512; off <<= 1) {
    int x = (t >= off) ? s[t - off] : 0;
    __syncthreads();
    s[t] += x;
    __syncthreads();
  }
  if (t < nb) bsum[t] = s[t] - v;  // exclusive
}

__global__ void k_scanC(int* __restrict__ rowstart, const int* __restrict__ bsum,
                        int n, int E) {
  int i = blockIdx.x * 256 + threadIdx.x;
  if (i < n) rowstart[i] += bsum[blockIdx.x];
  if (i == 0) rowstart[n] = E;
}

// combined {src, weight} 8B scatter
__global__ void k_fill(const int* __restrict__ src, const int* __restrict__ dst,
                       const float* __restrict__ dinv, const int* __restrict__ rowstart,
                       int* __restrict__ cursor, int2* __restrict__ csr_sw, int E) {
  int e = blockIdx.x * blockDim.x + threadIdx.x;
  if (e < E) {
    int d = dst[e], s = src[e];
    int pos = rowstart[d] + atomicAdd(&cursor[d], 1);
    csr_sw[pos] = make_int2(s, __float_as_int(dinv[s] * dinv[d]));
  }
}

// ---------- weight prep: fp32 [k][col] -> fp16 [col][k], 16 matrices ----------
__global__ __launch_bounds__(256) void k_wprep(const float* __restrict__ W1,
                                               const float* __restrict__ W2,
                                               _Float16* __restrict__ wt) {
  int m = blockIdx.x;
  const float* Wsrc = ((m & 1) ? W2 : W1) + (size_t)(m >> 1) * 16384;
  _Float16* Wdst = wt + (size_t)m * 16384;
  __shared__ _Float16 lds[128 * 132];
  int t = threadIdx.x;
  const float4* W4 = (const float4*)Wsrc;
  for (int it = 0; it < 16; ++it) {
    int idx = t + it * 256;
    int k = idx >> 5, c4 = idx & 31;
    float4 v = W4[idx];
    lds[(c4 * 4 + 0) * 132 + k] = (_Float16)v.x;
    lds[(c4 * 4 + 1) * 132 + k] = (_Float16)v.y;
    lds[(c4 * 4 + 2) * 132 + k] = (_Float16)v.z;
    lds[(c4 * 4 + 3) * 132 + k] = (_Float16)v.w;
  }
  __syncthreads();
  for (int it = 0; it < 16; ++it) {
    int idx = t + it * 256;
    int col = idx >> 5, k4 = idx & 31;
    f16x4 o;
    o[0] = lds[col * 132 + k4 * 4 + 0];
    o[1] = lds[col * 132 + k4 * 4 + 1];
    o[2] = lds[col * 132 + k4 * 4 + 2];
    o[3] = lds[col * 132 + k4 * 4 + 3];
    *(f16x4*)(Wdst + col * 128 + k4 * 4) = o;
  }
}

// ---------- fp32 VALU GEMM (projection only) ----------
__global__ __launch_bounds__(256) void k_gemmf(const float* __restrict__ in,
                                               const float* __restrict__ W,
                                               const float* __restrict__ bias,
                                               float* __restrict__ out, int n) {
  __shared__ float Ws[64 * 128];
  __shared__ float hs[64 * 68];
  int tid = threadIdx.x;
  int tx = tid & 15;
  int ty = tid >> 4;
  int row0 = blockIdx.x * 64;
  float acc[4][8];
#pragma unroll
  for (int i = 0; i < 4; i++)
#pragma unroll
    for (int j = 0; j < 8; j++) acc[i][j] = 0.f;

  for (int k0 = 0; k0 < 128; k0 += 64) {
    __syncthreads();
    for (int idx = tid; idx < 64 * 128 / 4; idx += 256) {
      float4 v = ((const float4*)(W + k0 * 128))[idx];
      ((float4*)Ws)[idx] = v;
    }
    for (int idx = tid; idx < 64 * 64 / 4; idx += 256) {
      int r = idx >> 4;
      int c4 = idx & 15;
      int row = row0 + r;
      if (row >= n) row = n - 1;
      float4 v = *(const float4*)(in + (size_t)row * 128 + k0 + c4 * 4);
      *(float4*)(hs + r * 68 + c4 * 4) = v;
    }
    __syncthreads();
#pragma unroll
    for (int kk = 0; kk < 64; kk += 4) {
      float4 a[4];
#pragma unroll
      for (int i = 0; i < 4; i++) a[i] = *(const float4*)(hs + (ty + 16 * i) * 68 + kk);
#pragma unroll
      for (int kq = 0; kq < 4; kq++) {
        float4 b0 = *(const float4*)(Ws + (kk + kq) * 128 + tx * 4);
        float4 b1 = *(const float4*)(Ws + (kk + kq) * 128 + 64 + tx * 4);
#pragma unroll
        for (int i = 0; i < 4; i++) {
          float aa = ((const float*)&a[i])[kq];
          acc[i][0] += aa * b0.x; acc[i][1] += aa * b0.y;
          acc[i][2] += aa * b0.z; acc[i][3] += aa * b0.w;
          acc[i][4] += aa * b1.x; acc[i][5] += aa * b1.y;
          acc[i][6] += aa * b1.z; acc[i][7] += aa * b1.w;
        }
      }
    }
  }
#pragma unroll
  for (int i = 0; i < 4; i++) {
    int row = row0 + ty + 16 * i;
    if (row < n) {
      float4 bb0 = *(const float4*)(bias + tx * 4);
      float4 bb1 = *(const float4*)(bias + 64 + tx * 4);
      *(float4*)(out + (size_t)row * 128 + tx * 4) =
          make_float4(acc[i][0] + bb0.x, acc[i][1] + bb0.y, acc[i][2] + bb0.z, acc[i][3] + bb0.w);
      *(float4*)(out + (size_t)row * 128 + 64 + tx * 4) =
          make_float4(acc[i][4] + bb1.x, acc[i][5] + bb1.y, acc[i][6] + bb1.z, acc[i][7] + bb1.w);
    }
  }
}

// ---------- MFMA f16 GEMM: outh[N,128] = xform(in)[N,128] @ W (fp16 out) ----------
template <int XFORM>
__global__ __launch_bounds__(256) void k_gemmh(const float* __restrict__ in,
                                               const _Float16* __restrict__ wt,
                                               const float* __restrict__ scale,
                                               const float* __restrict__ shift,
                                               _Float16* __restrict__ outh, int n) {
  __shared__ _Float16 As[64 * 128];
  __shared__ _Float16 Bs[128 * 128];
  char* Ap = (char*)As;
  char* Bp = (char*)Bs;
  int tid = threadIdx.x;
  int lane = tid & 63;
  int rt = tid >> 6;
  int row0 = blockIdx.x * 64;

  for (int it = 0; it < 8; ++it) {
    int idx = tid + it * 256;
    int r = idx >> 5, c4 = idx & 31;
    int row = row0 + r;
    if (row >= n) row = n - 1;
    float4 v = *(const float4*)(in + (size_t)row * 128 + c4 * 4);
    if (XFORM) {
      float4 sc = *(const float4*)(scale + c4 * 4);
      float4 sh = *(const float4*)(shift + c4 * 4);
      v.x = fmaxf(v.x * sc.x + sh.x, 0.f);
      v.y = fmaxf(v.y * sc.y + sh.y, 0.f);
      v.z = fmaxf(v.z * sc.z + sh.z, 0.f);
      v.w = fmaxf(v.w * sc.w + sh.w, 0.f);
    }
    f16x4 hv;
    hv[0] = (_Float16)v.x; hv[1] = (_Float16)v.y;
    hv[2] = (_Float16)v.z; hv[3] = (_Float16)v.w;
    *(f16x4*)(Ap + ((r * 256 + c4 * 8) ^ ((r & 7) << 4))) = hv;
  }
  for (int it = 0; it < 8; ++it) {
    int idx = tid + it * 256;
    int col = idx >> 4, k8 = idx & 15;
    f16x8 v = *(const f16x8*)(wt + col * 128 + k8 * 8);
    *(f16x8*)(Bp + ((col * 256 + k8 * 16) ^ ((col & 7) << 4))) = v;
  }
  __syncthreads();

  f32x4 acc[8];
#pragma unroll
  for (int ct = 0; ct < 8; ++ct) acc[ct] = (f32x4){0.f, 0.f, 0.f, 0.f};

  int arow = rt * 16 + (lane & 15);
  int kc = (lane >> 4) * 16;
#pragma unroll
  for (int ks = 0; ks < 4; ++ks) {
    int kb = ks * 64;
    f16x8 a = *(f16x8*)(Ap + ((arow * 256 + kb + kc) ^ ((arow & 7) << 4)));
#pragma unroll
    for (int ct = 0; ct < 8; ++ct) {
      int bcol = ct * 16 + (lane & 15);
      f16x8 b = *(f16x8*)(Bp + ((bcol * 256 + kb + kc) ^ ((bcol & 7) << 4)));
      acc[ct] = __builtin_amdgcn_mfma_f32_16x16x32_f16(a, b, acc[ct], 0, 0, 0);
    }
  }

  int orow0 = row0 + rt * 16 + (lane >> 4) * 4;
#pragma unroll
  for (int ct = 0; ct < 8; ++ct) {
    int col = ct * 16 + (lane & 15);
#pragma unroll
    for (int r = 0; r < 4; ++r) {
      int row = orow0 + r;
      if (row < n) outh[(size_t)row * 128 + col] = (_Float16)acc[ct][r];
    }
  }
}

// ---------- edge aggregation (wave-per-node, fp16 gather) + fused BN stats ----------
// out[n] = sum_e w_e*hw[src] + dinv[n]^2*hw[n] + b; psum/psq (replicated) += col stats
__global__ __launch_bounds__(256) void k_agg(const __half2* __restrict__ hw,
                                             const int* __restrict__ rowstart,
                                             const int2* __restrict__ csr_sw,
                                             const float* __restrict__ dinv,
                                             const float* __restrict__ bias,
                                             float* __restrict__ out,
                                             float* __restrict__ psum,
                                             float* __restrict__ psq, int n) {
  int wave = threadIdx.x >> 6;
  int lane = threadIdx.x & 63;
  int node = blockIdx.x * 4 + wave;
  float ax = 0.f, ay = 0.f;
  if (node < n) {
    int e0 = rowstart[node], e1 = rowstart[node + 1];
    float ax0 = 0.f, ay0 = 0.f, ax1 = 0.f, ay1 = 0.f;
    float ax2 = 0.f, ay2 = 0.f, ax3 = 0.f, ay3 = 0.f;
    int e = e0;
    for (; e + 3 < e1; e += 4) {
      int2 s0 = csr_sw[e], s1 = csr_sw[e + 1], s2 = csr_sw[e + 2], s3 = csr_sw[e + 3];
      float w0 = __int_as_float(s0.y), w1 = __int_as_float(s1.y);
      float w2 = __int_as_float(s2.y), w3 = __int_as_float(s3.y);
      float2 f0 = __half22float2(hw[(size_t)s0.x * 64 + lane]);
      float2 f1 = __half22float2(hw[(size_t)s1.x * 64 + lane]);
      float2 f2 = __half22float2(hw[(size_t)s2.x * 64 + lane]);
      float2 f3 = __half22float2(hw[(size_t)s3.x * 64 + lane]);
      ax0 += w0 * f0.x; ay0 += w0 * f0.y;
      ax1 += w1 * f1.x; ay1 += w1 * f1.y;
      ax2 += w2 * f2.x; ay2 += w2 * f2.y;
      ax3 += w3 * f3.x; ay3 += w3 * f3.y;
    }
    for (; e < e1; ++e) {
      int2 s0 = csr_sw[e];
      float w0 = __int_as_float(s0.y);
      float2 f0 = __half22float2(hw[(size_t)s0.x * 64 + lane]);
      ax0 += w0 * f0.x; ay0 += w0 * f0.y;
    }
    ax = (ax0 + ax1) + (ax2 + ax3);
    ay = (ay0 + ay1) + (ay2 + ay3);
    float dn = dinv[node];
    float sn = dn * dn;
    float2 v = __half22float2(hw[(size_t)node * 64 + lane]);
    float2 bb = *(const float2*)(bias + lane * 2);
    ax += sn * v.x + bb.x;
    ay += sn * v.y + bb.y;
    *(float2*)(out + (size_t)node * 128 + lane * 2) = make_float2(ax, ay);
  }
  // fused BN stats: LDS reduce over 4 waves, then replicated atomics
  __shared__ float ss[4][128];
  __shared__ float sq[4][128];
  ss[wave][lane * 2] = ax;       ss[wave][lane * 2 + 1] = ay;
  sq[wave][lane * 2] = ax * ax;  sq[wave][lane * 2 + 1] = ay * ay;
  __syncthreads();
  int t = threadIdx.x;
  if (t < 128) {
    float s = (ss[0][t] + ss[1][t]) + (ss[2][t] + ss[3][t]);
    float q = (sq[0][t] + sq[1][t]) + (sq[2][t] + sq[3][t]);
    int rep = blockIdx.x & (PS_REP - 1);
    atomicAdd(&psum[rep * 128 + t], s);
    atomicAdd(&psq[rep * 128 + t], q);
  }
}

// ---------- BN finalize: reduce replicas, re-zero them ----------
__global__ void k_bnfin(float* __restrict__ psum, float* __restrict__ psq,
                        const float* __restrict__ g, const float* __restrict__ be,
                        float* __restrict__ scale, float* __restrict__ shift, int n) {
  int c = threadIdx.x;  // 128
  float s = 0.f, q = 0.f;
  for (int r = 0; r < PS_REP; ++r) {
    s += psum[r * 128 + c];
    q += psq[r * 128 + c];
    psum[r * 128 + c] = 0.f;
    psq[r * 128 + c] = 0.f;
  }
  float mu = s / (float)n;
  float var = q / (float)n - mu * mu;
  float rs = rsqrtf(var + EPSBN);
  float sc = g[c] * rs;
  scale[c] = sc;
  shift[c] = be[c] - mu * sc;
}

// ---------- BN apply + residual ----------
__global__ __launch_bounds__(256) void k_bnresid(const float* __restrict__ x,
                                                 const float* __restrict__ scale,
                                                 const float* __restrict__ shift,
                                                 float* __restrict__ out, int n) {
  int idx = blockIdx.x * 256 + threadIdx.x;
  int total = n * 32;
  if (idx >= total) return;
  int c4 = idx & 31;
  float4 v = ((const float4*)x)[idx];
  float4 sc = ((const float4*)scale)[c4];
  float4 sh = ((const float4*)shift)[c4];
  float4 h = ((const float4*)out)[idx];
  ((float4*)out)[idx] = make_float4(v.x * sc.x + sh.x + h.x, v.y * sc.y + sh.y + h.y,
                                    v.z * sc.z + sh.z + h.z, v.w * sc.w + sh.w + h.w);
}

// ---------- pooling: batch sorted -> segment reduction ----------
#define PCHUNK 128
__global__ __launch_bounds__(128) void k_pool(const float* __restrict__ h,
                                              const int* __restrict__ batch,
                                              float* __restrict__ sums,
                                              unsigned* __restrict__ maxenc,
                                              int* __restrict__ cnt, int n) {
  int c = threadIdx.x;
  int start = blockIdx.x * PCHUNK;
  if (start >= n) return;
  int end = start + PCHUNK;
  if (end > n) end = n;
  int cur = batch[start];
  float s = 0.f, mx = -FLT_MAX;
  int runlen = 0;
  for (int i = start; i < end; ++i) {
    int b = batch[i];
    if (b != cur) {
      atomicAdd(&sums[cur * 128 + c], s);
      atomicMax(&maxenc[cur * 128 + c], enc_f(mx));
      if (c == 0) atomicAdd(&cnt[cur], runlen);
      s = 0.f; mx = -FLT_MAX; runlen = 0; cur = b;
    }
    float v = h[(size_t)i * 128 + c];
    s += v;
    mx = fmaxf(mx, v);
    runlen++;
  }
  atomicAdd(&sums[cur * 128 + c], s);
  atomicMax(&maxenc[cur * 128 + c], enc_f(mx));
  if (c == 0) atomicAdd(&cnt[cur], runlen);
}

// ---------- readout MLP ----------
__global__ __launch_bounds__(256) void k_readout(const float* __restrict__ sums,
                                                 const unsigned* __restrict__ maxenc,
                                                 const int* __restrict__ cnt,
                                                 const float* __restrict__ Wa,
                                                 const float* __restrict__ ba,
                                                 const float* __restrict__ Wb,
                                                 const float* __restrict__ bb,
                                                 const float* __restrict__ Wc,
                                                 const float* __restrict__ bc,
                                                 float* __restrict__ out) {
  int g = blockIdx.x;
  int t = threadIdx.x;
  __shared__ float z[384];
  __shared__ float za[256];
  __shared__ float zb[128];
  float c = (float)(cnt[g] > 1 ? cnt[g] : 1);
  if (t < 128) {
    float s = sums[g * 128 + t];
    z[t] = s / c;
    z[128 + t] = dec_f(maxenc[g * 128 + t]);
    z[256 + t] = s;
  }
  __syncthreads();
  float accA = ba[t];
  for (int k = 0; k < 384; k++) accA += z[k] * Wa[k * 256 + t];
  za[t] = fmaxf(accA, 0.f);
  __syncthreads();
  if (t < 128) {
    float accB = bb[t];
    for (int k = 0; k < 256; k++) accB += za[k] * Wb[k * 128 + t];
    zb[t] = fmaxf(accB, 0.f);
  }
  __syncthreads();
  if (t < 64) {
    float p = zb[t] * Wc[t] + zb[t + 64] * Wc[t + 64];
    for (int off = 32; off > 0; off >>= 1) p += __shfl_down(p, off);
    if (t == 0) out[g] = p + bc[0];
  }
}

extern "C" void kernel_launch(void* const* d_in, const int* in_sizes, int n_in,
                              void* d_out, int out_size, void* d_ws, size_t ws_size,
                              hipStream_t stream) {
  const float* x   = (const float*)d_in[0];
  const int* edge  = (const int*)d_in[1];
  const int* batch = (const int*)d_in[2];
  const float* Wp  = (const float*)d_in[3];
  const float* bp  = (const float*)d_in[4];
  const float* W1  = (const float*)d_in[5];
  const float* b1  = (const float*)d_in[6];
  const float* g1  = (const float*)d_in[7];
  const float* be1 = (const float*)d_in[8];
  const float* W2  = (const float*)d_in[9];
  const float* b2  = (const float*)d_in[10];
  const float* g2  = (const float*)d_in[11];
  const float* be2 = (const float*)d_in[12];
  const float* Wa  = (const float*)d_in[13];
  const float* ba  = (const float*)d_in[14];
  const float* Wb  = (const float*)d_in[15];
  const float* bbp = (const float*)d_in[16];
  const float* Wc  = (const float*)d_in[17];
  const float* bc  = (const float*)d_in[18];
  float* out = (float*)d_out;

  const int N = in_sizes[0] / 128;
  const int E = in_sizes[1] / 2;
  const int* esrc = edge;
  const int* edst = edge + E;

  char* p = (char*)d_ws;
  auto carve = [&](size_t bytes) {
    char* r = p;
    p += (bytes + 255) & ~(size_t)255;
    return (void*)r;
  };
  float* h    = (float*)carve((size_t)N * 128 * 4);
  _Float16* t1h = (_Float16*)carve((size_t)N * 128 * 2);
  float* t2   = (float*)carve((size_t)N * 128 * 4);
  int2* csr_sw = (int2*)carve((size_t)E * 8);
  int* deg     = (int*)carve((size_t)N * 4);
  float* dinv  = (float*)carve((size_t)N * 4);
  int* rowstart = (int*)carve((size_t)(N + 1) * 4);
  int* cursor   = (int*)carve((size_t)N * 4);
  int* bsum     = (int*)carve(512 * 4);
  float* psum   = (float*)carve((size_t)PS_REP * 128 * 2 * 4);  // psum + psq replicas
  float* psq    = psum + PS_REP * 128;
  float* scale  = (float*)carve(128 * 4);
  float* shift  = (float*)carve(128 * 4);
  float* pools  = (float*)carve((size_t)NGRAPH * 128 * 4);
  unsigned* poolm = (unsigned*)carve((size_t)NGRAPH * 128 * 4);
  int* poolc      = (int*)carve(NGRAPH * 4);
  _Float16* wt16  = (_Float16*)carve((size_t)16 * 128 * 128 * 2);

  const int NB = (N + 255) / 256;

  hipMemsetAsync(deg, 0, (size_t)N * 4, stream);
  hipMemsetAsync(cursor, 0, (size_t)N * 4, stream);
  hipMemsetAsync(psum, 0, (size_t)PS_REP * 128 * 2 * 4, stream);
  hipMemsetAsync(pools, 0, (size_t)NGRAPH * 128 * 4, stream);
  hipMemsetAsync(poolm, 0, (size_t)NGRAPH * 128 * 4, stream);
  hipMemsetAsync(poolc, 0, (size_t)NGRAPH * 4, stream);

  k_deg<<<(E + 255) / 256, 256, 0, stream>>>(edst, deg, E);
  k_dinv<<<NB, 256, 0, stream>>>(deg, dinv, N);
  k_scanA<<<NB, 256, 0, stream>>>(deg, rowstart, bsum, N);
  k_scanB<<<1, 512, 0, stream>>>(bsum, NB);
  k_scanC<<<NB, 256, 0, stream>>>(rowstart, bsum, N, E);
  k_fill<<<(E + 255) / 256, 256, 0, stream>>>(esrc, edst, dinv, rowstart, cursor, csr_sw, E);
  k_wprep<<<16, 256, 0, stream>>>(W1, W2, wt16);

  const int GB = (N + 63) / 64;
  const int AB = (N + 3) / 4;
  const int EB = (N * 32 + 255) / 256;
  const int PB = (N + PCHUNK - 1) / PCHUNK;

  k_gemmf<<<GB, 256, 0, stream>>>(x, Wp, bp, h, N);

  for (int l = 0; l < 8; l++) {
    const _Float16* w1t = wt16 + (size_t)(l * 2) * 16384;
    const _Float16* w2t = wt16 + (size_t)(l * 2 + 1) * 16384;
    k_gemmh<0><<<GB, 256, 0, stream>>>(h, w1t, nullptr, nullptr, t1h, N);
    k_agg<<<AB, 256, 0, stream>>>((const __half2*)t1h, rowstart, csr_sw, dinv, b1 + l * 128, t2, psum, psq, N);
    k_bnfin<<<1, 128, 0, stream>>>(psum, psq, g1 + l * 128, be1 + l * 128, scale, shift, N);
    k_gemmh<1><<<GB, 256, 0, stream>>>(t2, w2t, scale, shift, t1h, N);
    k_agg<<<AB, 256, 0, stream>>>((const __half2*)t1h, rowstart, csr_sw, dinv, b2 + l * 128, t2, psum, psq, N);
    k_bnfin<<<1, 128, 0, stream>>>(psum, psq, g2 + l * 128, be2 + l * 128, scale, shift, N);
    k_bnresid<<<EB, 256, 0, stream>>>(t2, scale, shift, h, N);
  }

  k_pool<<<PB, 128, 0, stream>>>(h, batch, pools, poolm, poolc, N);
  k_readout<<<NGRAPH, 256, 0, stream>>>(pools, poolm, poolc, Wa, ba, Wb, bbp, Wc, bc, out);
}

// Round 6
// 1935.055 us; speedup vs baseline: 3.2785x; 1.1211x over previous
//
#include <hip/hip_runtime.h>
#include <hip/hip_fp16.h>
#include <math.h>
#include <float.h>

#define HDIM 128
#define NGRAPH 256
#define EPSBN 1e-5f
#define PS_REP 32

typedef _Float16 f16x8 __attribute__((ext_vector_type(8)));
typedef _Float16 f16x4 __attribute__((ext_vector_type(4)));
typedef float f32x4 __attribute__((ext_vector_type(4)));

__device__ inline unsigned enc_f(float v) {
  unsigned u = __float_as_uint(v);
  return (u & 0x80000000u) ? ~u : (u | 0x80000000u);
}
__device__ inline float dec_f(unsigned e) {
  return __uint_as_float((e & 0x80000000u) ? (e ^ 0x80000000u) : ~e);
}

// ---------- degree / dinv ----------
__global__ void k_deg(const int* __restrict__ dst, int* __restrict__ deg, int E) {
  int i = blockIdx.x * blockDim.x + threadIdx.x;
  if (i < E) atomicAdd(&deg[dst[i]], 1);
}

__global__ void k_dinv(const int* __restrict__ deg, float* __restrict__ dinv, int n) {
  int i = blockIdx.x * blockDim.x + threadIdx.x;
  if (i < n) dinv[i] = rsqrtf((float)deg[i] + 1.0f);
}

// ---------- 2-level exclusive scan of PADDED deg (multiple of 8) -> prow ----------
__global__ void k_scanA(const int* __restrict__ deg, int* __restrict__ rowstart,
                        int* __restrict__ bsum, int n) {
  __shared__ int s[256];
  int t = threadIdx.x, i = blockIdx.x * 256 + t;
  int v = (i < n) ? ((deg[i] + 7) & ~7) : 0;
  s[t] = v;
  __syncthreads();
  for (int off = 1; off < 256; off <<= 1) {
    int x = (t >= off) ? s[t - off] : 0;
    __syncthreads();
    s[t] += x;
    __syncthreads();
  }
  if (i < n) rowstart[i] = s[t] - v;  // exclusive
  if (t == 255) bsum[blockIdx.x] = s[255];
}

__global__ void k_scanB(int* __restrict__ bsum, int nb) {
  __shared__ int s[512];
  int t = threadIdx.x;
  int v = (t < nb) ? bsum[t] : 0;
  s[t] = v;
  __syncthreads();
  for (int off = 1; off < 512; off <<= 1) {
    int x = (t >= off) ? s[t - off] : 0;
    __syncthreads();
    s[t] += x;
    __syncthreads();
  }
  if (t < nb) bsum[t] = s[t] - v;  // exclusive
}

__global__ void k_scanC(int* __restrict__ rowstart, const int* __restrict__ bsum,
                        const int* __restrict__ deg, int n) {
  int i = blockIdx.x * 256 + threadIdx.x;
  if (i < n) {
    int v = rowstart[i] + bsum[blockIdx.x];
    rowstart[i] = v;
    if (i == n - 1) rowstart[n] = v + ((deg[i] + 7) & ~7);
  }
}

// real edges -> padded CSR slots {src, w}
__global__ void k_fill(const int* __restrict__ src, const int* __restrict__ dst,
                       const float* __restrict__ dinv, const int* __restrict__ prow,
                       int* __restrict__ cursor, int2* __restrict__ csr_sw, int E) {
  int e = blockIdx.x * blockDim.x + threadIdx.x;
  if (e < E) {
    int d = dst[e], s = src[e];
    int pos = prow[d] + atomicAdd(&cursor[d], 1);
    csr_sw[pos] = make_int2(s, __float_as_int(dinv[s] * dinv[d]));
  }
}

// pad slots deg[i]..degpad-1 with {self, 0}
__global__ void k_pad(const int* __restrict__ deg, const int* __restrict__ prow,
                      int2* __restrict__ csr_sw, int n) {
  int i = blockIdx.x * blockDim.x + threadIdx.x;
  if (i < n) {
    int d = deg[i], dp = (d + 7) & ~7;
    int base = prow[i];
    for (int j = d; j < dp; ++j) csr_sw[base + j] = make_int2(i, 0);
  }
}

// ---------- weight prep: fp32 [k][col] -> fp16 [col][k], 16 matrices ----------
__global__ __launch_bounds__(256) void k_wprep(const float* __restrict__ W1,
                                               const float* __restrict__ W2,
                                               _Float16* __restrict__ wt) {
  int m = blockIdx.x;
  const float* Wsrc = ((m & 1) ? W2 : W1) + (size_t)(m >> 1) * 16384;
  _Float16* Wdst = wt + (size_t)m * 16384;
  __shared__ _Float16 lds[128 * 132];
  int t = threadIdx.x;
  const float4* W4 = (const float4*)Wsrc;
  for (int it = 0; it < 16; ++it) {
    int idx = t + it * 256;
    int k = idx >> 5, c4 = idx & 31;
    float4 v = W4[idx];
    lds[(c4 * 4 + 0) * 132 + k] = (_Float16)v.x;
    lds[(c4 * 4 + 1) * 132 + k] = (_Float16)v.y;
    lds[(c4 * 4 + 2) * 132 + k] = (_Float16)v.z;
    lds[(c4 * 4 + 3) * 132 + k] = (_Float16)v.w;
  }
  __syncthreads();
  for (int it = 0; it < 16; ++it) {
    int idx = t + it * 256;
    int col = idx >> 5, k4 = idx & 31;
    f16x4 o;
    o[0] = lds[col * 132 + k4 * 4 + 0];
    o[1] = lds[col * 132 + k4 * 4 + 1];
    o[2] = lds[col * 132 + k4 * 4 + 2];
    o[3] = lds[col * 132 + k4 * 4 + 3];
    *(f16x4*)(Wdst + col * 128 + k4 * 4) = o;
  }
}

// ---------- fp32 VALU GEMM (input projection only) ----------
__global__ __launch_bounds__(256) void k_gemmf(const float* __restrict__ in,
                                               const float* __restrict__ W,
                                               const float* __restrict__ bias,
                                               float* __restrict__ out, int n) {
  __shared__ float Ws[64 * 128];
  __shared__ float hs[64 * 68];
  int tid = threadIdx.x;
  int tx = tid & 15;
  int ty = tid >> 4;
  int row0 = blockIdx.x * 64;
  float acc[4][8];
#pragma unroll
  for (int i = 0; i < 4; i++)
#pragma unroll
    for (int j = 0; j < 8; j++) acc[i][j] = 0.f;

  for (int k0 = 0; k0 < 128; k0 += 64) {
    __syncthreads();
    for (int idx = tid; idx < 64 * 128 / 4; idx += 256) {
      float4 v = ((const float4*)(W + k0 * 128))[idx];
      ((float4*)Ws)[idx] = v;
    }
    for (int idx = tid; idx < 64 * 64 / 4; idx += 256) {
      int r = idx >> 4;
      int c4 = idx & 15;
      int row = row0 + r;
      if (row >= n) row = n - 1;
      float4 v = *(const float4*)(in + (size_t)row * 128 + k0 + c4 * 4);
      *(float4*)(hs + r * 68 + c4 * 4) = v;
    }
    __syncthreads();
#pragma unroll
    for (int kk = 0; kk < 64; kk += 4) {
      float4 a[4];
#pragma unroll
      for (int i = 0; i < 4; i++) a[i] = *(const float4*)(hs + (ty + 16 * i) * 68 + kk);
#pragma unroll
      for (int kq = 0; kq < 4; kq++) {
        float4 b0 = *(const float4*)(Ws + (kk + kq) * 128 + tx * 4);
        float4 b1 = *(const float4*)(Ws + (kk + kq) * 128 + 64 + tx * 4);
#pragma unroll
        for (int i = 0; i < 4; i++) {
          float aa = ((const float*)&a[i])[kq];
          acc[i][0] += aa * b0.x; acc[i][1] += aa * b0.y;
          acc[i][2] += aa * b0.z; acc[i][3] += aa * b0.w;
          acc[i][4] += aa * b1.x; acc[i][5] += aa * b1.y;
          acc[i][6] += aa * b1.z; acc[i][7] += aa * b1.w;
        }
      }
    }
  }
#pragma unroll
  for (int i = 0; i < 4; i++) {
    int row = row0 + ty + 16 * i;
    if (row < n) {
      float4 bb0 = *(const float4*)(bias + tx * 4);
      float4 bb1 = *(const float4*)(bias + 64 + tx * 4);
      *(float4*)(out + (size_t)row * 128 + tx * 4) =
          make_float4(acc[i][0] + bb0.x, acc[i][1] + bb0.y, acc[i][2] + bb0.z, acc[i][3] + bb0.w);
      *(float4*)(out + (size_t)row * 128 + 64 + tx * 4) =
          make_float4(acc[i][4] + bb1.x, acc[i][5] + bb1.y, acc[i][6] + bb1.z, acc[i][7] + bb1.w);
    }
  }
}

// ---------- MFMA f16 GEMM: outh[N,128] = xform(in)[N,128] @ W (fp16 out) ----------
// XFORM=0: plain. XFORM=1: in := relu(in*scale+shift).
// XFORM=2: in := hres + in*scale+shift (BN2+residual), also writes new hres.
template <int XFORM>
__global__ __launch_bounds__(256) void k_gemmh(const float* __restrict__ in,
                                               const _Float16* __restrict__ wt,
                                               const float* __restrict__ scale,
                                               const float* __restrict__ shift,
                                               float* __restrict__ hres,
                                               _Float16* __restrict__ outh, int n) {
  __shared__ _Float16 As[64 * 128];
  __shared__ _Float16 Bs[128 * 128];
  char* Ap = (char*)As;
  char* Bp = (char*)Bs;
  int tid = threadIdx.x;
  int lane = tid & 63;
  int rt = tid >> 6;
  int row0 = blockIdx.x * 64;

  for (int it = 0; it < 8; ++it) {
    int idx = tid + it * 256;
    int r = idx >> 5, c4 = idx & 31;
    int rrow = row0 + r;
    int row = (rrow >= n) ? (n - 1) : rrow;
    float4 v = *(const float4*)(in + (size_t)row * 128 + c4 * 4);
    if (XFORM == 1) {
      float4 sc = *(const float4*)(scale + c4 * 4);
      float4 sh = *(const float4*)(shift + c4 * 4);
      v.x = fmaxf(v.x * sc.x + sh.x, 0.f);
      v.y = fmaxf(v.y * sc.y + sh.y, 0.f);
      v.z = fmaxf(v.z * sc.z + sh.z, 0.f);
      v.w = fmaxf(v.w * sc.w + sh.w, 0.f);
    }
    if (XFORM == 2) {
      float4 sc = *(const float4*)(scale + c4 * 4);
      float4 sh = *(const float4*)(shift + c4 * 4);
      float4 hv = *(const float4*)(hres + (size_t)row * 128 + c4 * 4);
      v.x = v.x * sc.x + sh.x + hv.x;
      v.y = v.y * sc.y + sh.y + hv.y;
      v.z = v.z * sc.z + sh.z + hv.z;
      v.w = v.w * sc.w + sh.w + hv.w;
      if (rrow < n) *(float4*)(hres + (size_t)row * 128 + c4 * 4) = v;
    }
    f16x4 hv16;
    hv16[0] = (_Float16)v.x; hv16[1] = (_Float16)v.y;
    hv16[2] = (_Float16)v.z; hv16[3] = (_Float16)v.w;
    *(f16x4*)(Ap + ((r * 256 + c4 * 8) ^ ((r & 7) << 4))) = hv16;
  }
  for (int it = 0; it < 8; ++it) {
    int idx = tid + it * 256;
    int col = idx >> 4, k8 = idx & 15;
    f16x8 v = *(const f16x8*)(wt + col * 128 + k8 * 8);
    *(f16x8*)(Bp + ((col * 256 + k8 * 16) ^ ((col & 7) << 4))) = v;
  }
  __syncthreads();

  f32x4 acc[8];
#pragma unroll
  for (int ct = 0; ct < 8; ++ct) acc[ct] = (f32x4){0.f, 0.f, 0.f, 0.f};

  int arow = rt * 16 + (lane & 15);
  int kc = (lane >> 4) * 16;
#pragma unroll
  for (int ks = 0; ks < 4; ++ks) {
    int kb = ks * 64;
    f16x8 a = *(f16x8*)(Ap + ((arow * 256 + kb + kc) ^ ((arow & 7) << 4)));
#pragma unroll
    for (int ct = 0; ct < 8; ++ct) {
      int bcol = ct * 16 + (lane & 15);
      f16x8 b = *(f16x8*)(Bp + ((bcol * 256 + kb + kc) ^ ((bcol & 7) << 4)));
      acc[ct] = __builtin_amdgcn_mfma_f32_16x16x32_f16(a, b, acc[ct], 0, 0, 0);
    }
  }

  int orow0 = row0 + rt * 16 + (lane >> 4) * 4;
#pragma unroll
  for (int ct = 0; ct < 8; ++ct) {
    int col = ct * 16 + (lane & 15);
#pragma unroll
    for (int r = 0; r < 4; ++r) {
      int row = orow0 + r;
      if (row < n) outh[(size_t)row * 128 + col] = (_Float16)acc[ct][r];
    }
  }
}

// ---------- edge aggregation: wave-per-node, dual-edge lane-split gather ----------
// lanes 0..31 gather even edges, 32..63 odd edges; f16x4 (8B) per lane.
// padded CSR (multiple of 8 edges/node, pad w=0) -> branch-free 8-edge loop.
__global__ __launch_bounds__(256) void k_agg(const _Float16* __restrict__ hw,
                                             const int* __restrict__ prow,
                                             const int4* __restrict__ csr4,
                                             const float* __restrict__ dinv,
                                             const float* __restrict__ bias,
                                             float* __restrict__ out,
                                             float* __restrict__ psum,
                                             float* __restrict__ psq, int n) {
  int wave = threadIdx.x >> 6;
  int lane = threadIdx.x & 63;
  int half = lane >> 5;
  int l32 = lane & 31;
  int node = blockIdx.x * 4 + wave;
  float r0 = 0.f, r1 = 0.f, r2 = 0.f, r3 = 0.f;
  if (node < n) {
    int q0 = prow[node] >> 1, q1 = prow[node + 1] >> 1;  // int4-pair indices
    float a0[4] = {0, 0, 0, 0}, a1[4] = {0, 0, 0, 0};
    float a2[4] = {0, 0, 0, 0}, a3[4] = {0, 0, 0, 0};
    for (int q = q0; q < q1; q += 4) {
      int4 p0 = csr4[q], p1 = csr4[q + 1], p2 = csr4[q + 2], p3 = csr4[q + 3];
      int s0 = half ? p0.z : p0.x;  float w0 = __int_as_float(half ? p0.w : p0.y);
      int s1 = half ? p1.z : p1.x;  float w1 = __int_as_float(half ? p1.w : p1.y);
      int s2 = half ? p2.z : p2.x;  float w2 = __int_as_float(half ? p2.w : p2.y);
      int s3 = half ? p3.z : p3.x;  float w3 = __int_as_float(half ? p3.w : p3.y);
      f16x4 v0 = *(const f16x4*)(hw + (size_t)s0 * 128 + l32 * 4);
      f16x4 v1 = *(const f16x4*)(hw + (size_t)s1 * 128 + l32 * 4);
      f16x4 v2 = *(const f16x4*)(hw + (size_t)s2 * 128 + l32 * 4);
      f16x4 v3 = *(const f16x4*)(hw + (size_t)s3 * 128 + l32 * 4);
#pragma unroll
      for (int j = 0; j < 4; ++j) {
        a0[j] += w0 * (float)v0[j];
        a1[j] += w1 * (float)v1[j];
        a2[j] += w2 * (float)v2[j];
        a3[j] += w3 * (float)v3[j];
      }
    }
    r0 = (a0[0] + a1[0]) + (a2[0] + a3[0]);
    r1 = (a0[1] + a1[1]) + (a2[1] + a3[1]);
    r2 = (a0[2] + a1[2]) + (a2[2] + a3[2]);
    r3 = (a0[3] + a1[3]) + (a2[3] + a3[3]);
    // combine even/odd halves (lane i <-> lane i^32), then add self-loop + bias
    r0 += __shfl_xor(r0, 32);
    r1 += __shfl_xor(r1, 32);
    r2 += __shfl_xor(r2, 32);
    r3 += __shfl_xor(r3, 32);
    float dn = dinv[node];
    float sn = dn * dn;
    f16x4 v = *(const f16x4*)(hw + (size_t)node * 128 + l32 * 4);
    float4 bb = *(const float4*)(bias + l32 * 4);
    r0 += sn * (float)v[0] + bb.x;
    r1 += sn * (float)v[1] + bb.y;
    r2 += sn * (float)v[2] + bb.z;
    r3 += sn * (float)v[3] + bb.w;
    if (half == 0)
      *(float4*)(out + (size_t)node * 128 + l32 * 4) = make_float4(r0, r1, r2, r3);
  }
  // fused BN stats
  __shared__ float ss[4][128];
  __shared__ float sq[4][128];
  if (half == 0) {
    float vv0 = (node < n) ? r0 : 0.f;
    float vv1 = (node < n) ? r1 : 0.f;
    float vv2 = (node < n) ? r2 : 0.f;
    float vv3 = (node < n) ? r3 : 0.f;
    *(float4*)&ss[wave][l32 * 4] = make_float4(vv0, vv1, vv2, vv3);
    *(float4*)&sq[wave][l32 * 4] = make_float4(vv0 * vv0, vv1 * vv1, vv2 * vv2, vv3 * vv3);
  }
  __syncthreads();
  int t = threadIdx.x;
  if (t < 128) {
    float s = (ss[0][t] + ss[1][t]) + (ss[2][t] + ss[3][t]);
    float q = (sq[0][t] + sq[1][t]) + (sq[2][t] + sq[3][t]);
    int rep = blockIdx.x & (PS_REP - 1);
    atomicAdd(&psum[rep * 128 + t], s);
    atomicAdd(&psq[rep * 128 + t], q);
  }
}

// ---------- BN finalize ----------
__global__ void k_bnfin(float* __restrict__ psum, float* __restrict__ psq,
                        const float* __restrict__ g, const float* __restrict__ be,
                        float* __restrict__ scale, float* __restrict__ shift, int n) {
  int c = threadIdx.x;  // 128
  float s = 0.f, q = 0.f;
  for (int r = 0; r < PS_REP; ++r) {
    s += psum[r * 128 + c];
    q += psq[r * 128 + c];
    psum[r * 128 + c] = 0.f;
    psq[r * 128 + c] = 0.f;
  }
  float mu = s / (float)n;
  float var = q / (float)n - mu * mu;
  float rs = rsqrtf(var + EPSBN);
  float sc = g[c] * rs;
  scale[c] = sc;
  shift[c] = be[c] - mu * sc;
}

// ---------- BN apply + residual (last layer only) ----------
__global__ __launch_bounds__(256) void k_bnresid(const float* __restrict__ x,
                                                 const float* __restrict__ scale,
                                                 const float* __restrict__ shift,
                                                 float* __restrict__ out, int n) {
  int idx = blockIdx.x * 256 + threadIdx.x;
  int total = n * 32;
  if (idx >= total) return;
  int c4 = idx & 31;
  float4 v = ((const float4*)x)[idx];
  float4 sc = ((const float4*)scale)[c4];
  float4 sh = ((const float4*)shift)[c4];
  float4 h = ((const float4*)out)[idx];
  ((float4*)out)[idx] = make_float4(v.x * sc.x + sh.x + h.x, v.y * sc.y + sh.y + h.y,
                                    v.z * sc.z + sh.z + h.z, v.w * sc.w + sh.w + h.w);
}

// ---------- pooling: batch sorted -> segment reduction ----------
#define PCHUNK 128
__global__ __launch_bounds__(128) void k_pool(const float* __restrict__ h,
                                              const int* __restrict__ batch,
                                              float* __restrict__ sums,
                                              unsigned* __restrict__ maxenc,
                                              int* __restrict__ cnt, int n) {
  int c = threadIdx.x;
  int start = blockIdx.x * PCHUNK;
  if (start >= n) return;
  int end = start + PCHUNK;
  if (end > n) end = n;
  int cur = batch[start];
  float s = 0.f, mx = -FLT_MAX;
  int runlen = 0;
  for (int i = start; i < end; ++i) {
    int b = batch[i];
    if (b != cur) {
      atomicAdd(&sums[cur * 128 + c], s);
      atomicMax(&maxenc[cur * 128 + c], enc_f(mx));
      if (c == 0) atomicAdd(&cnt[cur], runlen);
      s = 0.f; mx = -FLT_MAX; runlen = 0; cur = b;
    }
    float v = h[(size_t)i * 128 + c];
    s += v;
    mx = fmaxf(mx, v);
    runlen++;
  }
  atomicAdd(&sums[cur * 128 + c], s);
  atomicMax(&maxenc[cur * 128 + c], enc_f(mx));
  if (c == 0) atomicAdd(&cnt[cur], runlen);
}

// ---------- readout MLP ----------
__global__ __launch_bounds__(256) void k_readout(const float* __restrict__ sums,
                                                 const unsigned* __restrict__ maxenc,
                                                 const int* __restrict__ cnt,
                                                 const float* __restrict__ Wa,
                                                 const float* __restrict__ ba,
                                                 const float* __restrict__ Wb,
                                                 const float* __restrict__ bb,
                                                 const float* __restrict__ Wc,
                                                 const float* __restrict__ bc,
                                                 float* __restrict__ out) {
  int g = blockIdx.x;
  int t = threadIdx.x;
  __shared__ float z[384];
  __shared__ float za[256];
  __shared__ float zb[128];
  float c = (float)(cnt[g] > 1 ? cnt[g] : 1);
  if (t < 128) {
    float s = sums[g * 128 + t];
    z[t] = s / c;
    z[128 + t] = dec_f(maxenc[g * 128 + t]);
    z[256 + t] = s;
  }
  __syncthreads();
  float accA = ba[t];
  for (int k = 0; k < 384; k++) accA += z[k] * Wa[k * 256 + t];
  za[t] = fmaxf(accA, 0.f);
  __syncthreads();
  if (t < 128) {
    float accB = bb[t];
    for (int k = 0; k < 256; k++) accB += za[k] * Wb[k * 128 + t];
    zb[t] = fmaxf(accB, 0.f);
  }
  __syncthreads();
  if (t < 64) {
    float p = zb[t] * Wc[t] + zb[t + 64] * Wc[t + 64];
    for (int off = 32; off > 0; off >>= 1) p += __shfl_down(p, off);
    if (t == 0) out[g] = p + bc[0];
  }
}

extern "C" void kernel_launch(void* const* d_in, const int* in_sizes, int n_in,
                              void* d_out, int out_size, void* d_ws, size_t ws_size,
                              hipStream_t stream) {
  const float* x   = (const float*)d_in[0];
  const int* edge  = (const int*)d_in[1];
  const int* batch = (const int*)d_in[2];
  const float* Wp  = (const float*)d_in[3];
  const float* bp  = (const float*)d_in[4];
  const float* W1  = (const float*)d_in[5];
  const float* b1  = (const float*)d_in[6];
  const float* g1  = (const float*)d_in[7];
  const float* be1 = (const float*)d_in[8];
  const float* W2  = (const float*)d_in[9];
  const float* b2  = (const float*)d_in[10];
  const float* g2  = (const float*)d_in[11];
  const float* be2 = (const float*)d_in[12];
  const float* Wa  = (const float*)d_in[13];
  const float* ba  = (const float*)d_in[14];
  const float* Wb  = (const float*)d_in[15];
  const float* bbp = (const float*)d_in[16];
  const float* Wc  = (const float*)d_in[17];
  const float* bc  = (const float*)d_in[18];
  float* out = (float*)d_out;

  const int N = in_sizes[0] / 128;
  const int E = in_sizes[1] / 2;
  const int* esrc = edge;
  const int* edst = edge + E;

  char* p = (char*)d_ws;
  auto carve = [&](size_t bytes) {
    char* r = p;
    p += (bytes + 255) & ~(size_t)255;
    return (void*)r;
  };
  float* h    = (float*)carve((size_t)N * 128 * 4);
  _Float16* t1h = (_Float16*)carve((size_t)N * 128 * 2);
  float* t2   = (float*)carve((size_t)N * 128 * 4);
  int2* csr_sw = (int2*)carve(((size_t)E + 8 * (size_t)N) * 8);  // padded CSR
  int* deg     = (int*)carve((size_t)N * 4);
  float* dinv  = (float*)carve((size_t)N * 4);
  int* prow    = (int*)carve((size_t)(N + 1) * 4);
  int* cursor  = (int*)carve((size_t)N * 4);
  int* bsum    = (int*)carve(512 * 4);
  float* psum  = (float*)carve((size_t)PS_REP * 128 * 2 * 4);
  float* psq   = psum + PS_REP * 128;
  float* scale = (float*)carve(128 * 4);
  float* shift = (float*)carve(128 * 4);
  float* pools = (float*)carve((size_t)NGRAPH * 128 * 4);
  unsigned* poolm = (unsigned*)carve((size_t)NGRAPH * 128 * 4);
  int* poolc      = (int*)carve(NGRAPH * 4);
  _Float16* wt16  = (_Float16*)carve((size_t)16 * 128 * 128 * 2);

  const int NB = (N + 255) / 256;

  hipMemsetAsync(deg, 0, (size_t)N * 4, stream);
  hipMemsetAsync(cursor, 0, (size_t)N * 4, stream);
  hipMemsetAsync(psum, 0, (size_t)PS_REP * 128 * 2 * 4, stream);
  hipMemsetAsync(pools, 0, (size_t)NGRAPH * 128 * 4, stream);
  hipMemsetAsync(poolm, 0, (size_t)NGRAPH * 128 * 4, stream);
  hipMemsetAsync(poolc, 0, (size_t)NGRAPH * 4, stream);

  k_deg<<<(E + 255) / 256, 256, 0, stream>>>(edst, deg, E);
  k_dinv<<<NB, 256, 0, stream>>>(deg, dinv, N);
  k_scanA<<<NB, 256, 0, stream>>>(deg, prow, bsum, N);
  k_scanB<<<1, 512, 0, stream>>>(bsum, NB);
  k_scanC<<<NB, 256, 0, stream>>>(prow, bsum, deg, N);
  k_fill<<<(E + 255) / 256, 256, 0, stream>>>(esrc, edst, dinv, prow, cursor, csr_sw, E);
  k_pad<<<NB, 256, 0, stream>>>(deg, prow, csr_sw, N);
  k_wprep<<<16, 256, 0, stream>>>(W1, W2, wt16);

  const int GB = (N + 63) / 64;
  const int AB = (N + 3) / 4;
  const int EB = (N * 32 + 255) / 256;
  const int PB = (N + PCHUNK - 1) / PCHUNK;

  k_gemmf<<<GB, 256, 0, stream>>>(x, Wp, bp, h, N);

  for (int l = 0; l < 8; l++) {
    const _Float16* w1t = wt16 + (size_t)(l * 2) * 16384;
    const _Float16* w2t = wt16 + (size_t)(l * 2 + 1) * 16384;
    if (l == 0) {
      k_gemmh<0><<<GB, 256, 0, stream>>>(h, w1t, nullptr, nullptr, nullptr, t1h, N);
    }
    // else: t1h already produced by previous layer's fused gemmh<2>
    k_agg<<<AB, 256, 0, stream>>>(t1h, prow, (const int4*)csr_sw, dinv, b1 + l * 128, t2, psum, psq, N);
    k_bnfin<<<1, 128, 0, stream>>>(psum, psq, g1 + l * 128, be1 + l * 128, scale, shift, N);
    k_gemmh<1><<<GB, 256, 0, stream>>>(t2, w2t, scale, shift, nullptr, t1h, N);
    k_agg<<<AB, 256, 0, stream>>>(t1h, prow, (const int4*)csr_sw, dinv, b2 + l * 128, t2, psum, psq, N);
    k_bnfin<<<1, 128, 0, stream>>>(psum, psq, g2 + l * 128, be2 + l * 128, scale, shift, N);
    if (l < 7) {
      // fused: h += bn2(t2); t1h = f16(h) @ W1[l+1]
      const _Float16* w1n = wt16 + (size_t)((l + 1) * 2) * 16384;
      k_gemmh<2><<<GB, 256, 0, stream>>>(t2, w1n, scale, shift, h, t1h, N);
    } else {
      k_bnresid<<<EB, 256, 0, stream>>>(t2, scale, shift, h, N);
    }
  }

  k_pool<<<PB, 128, 0, stream>>>(h, batch, pools, poolm, poolc, N);
  k_readout<<<NGRAPH, 256, 0, stream>>>(pools, poolm, poolc, Wa, ba, Wb, bbp, Wc, bc, out);
}

// Round 7
// 1872.954 us; speedup vs baseline: 3.3872x; 1.0332x over previous
//
#include <hip/hip_runtime.h>
#include <hip/hip_fp16.h>
#include <math.h>
#include <float.h>

#define HDIM 128
#define NGRAPH 256
#define EPSBN 1e-5f
#define PS_REP 32
#define SLABF (2 * PS_REP * 128)   // floats per BN slab (psum+psq)

typedef _Float16 f16x8 __attribute__((ext_vector_type(8)));
typedef _Float16 f16x4 __attribute__((ext_vector_type(4)));
typedef float f32x4 __attribute__((ext_vector_type(4)));

__device__ inline unsigned enc_f(float v) {
  unsigned u = __float_as_uint(v);
  return (u & 0x80000000u) ? ~u : (u | 0x80000000u);
}
__device__ inline float dec_f(unsigned e) {
  return __uint_as_float((e & 0x80000000u) ? (e ^ 0x80000000u) : ~e);
}

// ---------- degree / dinv ----------
__global__ void k_deg(const int* __restrict__ dst, int* __restrict__ deg, int E) {
  int i = blockIdx.x * blockDim.x + threadIdx.x;
  if (i < E) atomicAdd(&deg[dst[i]], 1);
}

__global__ void k_dinv(const int* __restrict__ deg, float* __restrict__ dinv, int n) {
  int i = blockIdx.x * blockDim.x + threadIdx.x;
  if (i < n) dinv[i] = rsqrtf((float)deg[i] + 1.0f);
}

// ---------- 2-level exclusive scan of PADDED deg (multiple of 8) -> prow ----------
__global__ void k_scanA(const int* __restrict__ deg, int* __restrict__ rowstart,
                        int* __restrict__ bsum, int n) {
  __shared__ int s[256];
  int t = threadIdx.x, i = blockIdx.x * 256 + t;
  int v = (i < n) ? ((deg[i] + 7) & ~7) : 0;
  s[t] = v;
  __syncthreads();
  for (int off = 1; off < 256; off <<= 1) {
    int x = (t >= off) ? s[t - off] : 0;
    __syncthreads();
    s[t] += x;
    __syncthreads();
  }
  if (i < n) rowstart[i] = s[t] - v;  // exclusive
  if (t == 255) bsum[blockIdx.x] = s[255];
}

__global__ void k_scanB(int* __restrict__ bsum, int nb) {
  __shared__ int s[512];
  int t = threadIdx.x;
  int v = (t < nb) ? bsum[t] : 0;
  s[t] = v;
  __syncthreads();
  for (int off = 1; off < 512; off <<= 1) {
    int x = (t >= off) ? s[t - off] : 0;
    __syncthreads();
    s[t] += x;
    __syncthreads();
  }
  if (t < nb) bsum[t] = s[t] - v;  // exclusive
}

__global__ void k_scanC(int* __restrict__ rowstart, const int* __restrict__ bsum,
                        const int* __restrict__ deg, int n) {
  int i = blockIdx.x * 256 + threadIdx.x;
  if (i < n) {
    int v = rowstart[i] + bsum[blockIdx.x];
    rowstart[i] = v;
    if (i == n - 1) rowstart[n] = v + ((deg[i] + 7) & ~7);
  }
}

// real edges -> padded CSR slots {src, w}
__global__ void k_fill(const int* __restrict__ src, const int* __restrict__ dst,
                       const float* __restrict__ dinv, const int* __restrict__ prow,
                       int* __restrict__ cursor, int2* __restrict__ csr_sw, int E) {
  int e = blockIdx.x * blockDim.x + threadIdx.x;
  if (e < E) {
    int d = dst[e], s = src[e];
    int pos = prow[d] + atomicAdd(&cursor[d], 1);
    csr_sw[pos] = make_int2(s, __float_as_int(dinv[s] * dinv[d]));
  }
}

// pad slots deg[i]..degpad-1 with {self, 0}
__global__ void k_pad(const int* __restrict__ deg, const int* __restrict__ prow,
                      int2* __restrict__ csr_sw, int n) {
  int i = blockIdx.x * blockDim.x + threadIdx.x;
  if (i < n) {
    int d = deg[i], dp = (d + 7) & ~7;
    int base = prow[i];
    for (int j = d; j < dp; ++j) csr_sw[base + j] = make_int2(i, 0);
  }
}

// ---------- weight prep: fp32 [k][col] -> fp16 [col][k], 17 matrices (16 layers + Wp) ----------
__global__ __launch_bounds__(256) void k_wprep(const float* __restrict__ W1,
                                               const float* __restrict__ W2,
                                               const float* __restrict__ Wp,
                                               _Float16* __restrict__ wt) {
  int m = blockIdx.x;
  const float* Wsrc = (m == 16) ? Wp : (((m & 1) ? W2 : W1) + (size_t)(m >> 1) * 16384);
  _Float16* Wdst = wt + (size_t)m * 16384;
  __shared__ _Float16 lds[128 * 132];
  int t = threadIdx.x;
  const float4* W4 = (const float4*)Wsrc;
  for (int it = 0; it < 16; ++it) {
    int idx = t + it * 256;
    int k = idx >> 5, c4 = idx & 31;
    float4 v = W4[idx];
    lds[(c4 * 4 + 0) * 132 + k] = (_Float16)v.x;
    lds[(c4 * 4 + 1) * 132 + k] = (_Float16)v.y;
    lds[(c4 * 4 + 2) * 132 + k] = (_Float16)v.z;
    lds[(c4 * 4 + 3) * 132 + k] = (_Float16)v.w;
  }
  __syncthreads();
  for (int it = 0; it < 16; ++it) {
    int idx = t + it * 256;
    int col = idx >> 5, k4 = idx & 31;
    f16x4 o;
    o[0] = lds[col * 132 + k4 * 4 + 0];
    o[1] = lds[col * 132 + k4 * 4 + 1];
    o[2] = lds[col * 132 + k4 * 4 + 2];
    o[3] = lds[col * 132 + k4 * 4 + 3];
    *(f16x4*)(Wdst + col * 128 + k4 * 4) = o;
  }
}

// ---------- MFMA projection: out[N,128] = f16(in) @ Wp + bias (fp32 out) ----------
__global__ __launch_bounds__(256) void k_gemmp(const float* __restrict__ in,
                                               const _Float16* __restrict__ wt,
                                               const float* __restrict__ bias,
                                               float* __restrict__ out, int n) {
  __shared__ _Float16 As[64 * 128];
  __shared__ _Float16 Bs[128 * 128];
  char* Ap = (char*)As;
  char* Bp = (char*)Bs;
  int tid = threadIdx.x;
  int lane = tid & 63;
  int rt = tid >> 6;
  int row0 = blockIdx.x * 64;

  for (int it = 0; it < 8; ++it) {
    int idx = tid + it * 256;
    int r = idx >> 5, c4 = idx & 31;
    int row = row0 + r;
    if (row >= n) row = n - 1;
    float4 v = *(const float4*)(in + (size_t)row * 128 + c4 * 4);
    f16x4 hv;
    hv[0] = (_Float16)v.x; hv[1] = (_Float16)v.y;
    hv[2] = (_Float16)v.z; hv[3] = (_Float16)v.w;
    *(f16x4*)(Ap + ((r * 256 + c4 * 8) ^ ((r & 7) << 4))) = hv;
  }
  for (int it = 0; it < 8; ++it) {
    int idx = tid + it * 256;
    int col = idx >> 4, k8 = idx & 15;
    f16x8 v = *(const f16x8*)(wt + col * 128 + k8 * 8);
    *(f16x8*)(Bp + ((col * 256 + k8 * 16) ^ ((col & 7) << 4))) = v;
  }
  __syncthreads();

  f32x4 acc[8];
#pragma unroll
  for (int ct = 0; ct < 8; ++ct) acc[ct] = (f32x4){0.f, 0.f, 0.f, 0.f};
  int arow = rt * 16 + (lane & 15);
  int kc = (lane >> 4) * 16;
#pragma unroll
  for (int ks = 0; ks < 4; ++ks) {
    int kb = ks * 64;
    f16x8 a = *(f16x8*)(Ap + ((arow * 256 + kb + kc) ^ ((arow & 7) << 4)));
#pragma unroll
    for (int ct = 0; ct < 8; ++ct) {
      int bcol = ct * 16 + (lane & 15);
      f16x8 b = *(f16x8*)(Bp + ((bcol * 256 + kb + kc) ^ ((bcol & 7) << 4)));
      acc[ct] = __builtin_amdgcn_mfma_f32_16x16x32_f16(a, b, acc[ct], 0, 0, 0);
    }
  }

  int orow0 = row0 + rt * 16 + (lane >> 4) * 4;
#pragma unroll
  for (int ct = 0; ct < 8; ++ct) {
    int col = ct * 16 + (lane & 15);
    float bb = bias[col];
#pragma unroll
    for (int r = 0; r < 4; ++r) {
      int row = orow0 + r;
      if (row < n) out[(size_t)row * 128 + col] = acc[ct][r] + bb;
    }
  }
}

// ---------- MFMA f16 GEMM with BN prologue ----------
// XFORM=0: plain (in fp32 -> f16 stage). psumL/gg/be unused.
// XFORM=1: in := relu(in*sc+sh); sc/sh computed per-block from psumL slab.
// XFORM=2: in := hres + in*sc+sh (BN2+residual); writes new hres.
template <int XFORM>
__global__ __launch_bounds__(256) void k_gemmh(const float* __restrict__ in,
                                               const _Float16* __restrict__ wt,
                                               const float* __restrict__ psumL,
                                               const float* __restrict__ gg,
                                               const float* __restrict__ be,
                                               float* __restrict__ hres,
                                               _Float16* __restrict__ outh, int n) {
  __shared__ _Float16 As[64 * 128];
  __shared__ _Float16 Bs[128 * 128];
  __shared__ float sc_s[128], sh_s[128];
  char* Ap = (char*)As;
  char* Bp = (char*)Bs;
  int tid = threadIdx.x;
  int lane = tid & 63;
  int rt = tid >> 6;
  int row0 = blockIdx.x * 64;

  if (XFORM) {
    if (tid < 128) {
      const float* psqL = psumL + PS_REP * 128;
      float s = 0.f, q = 0.f;
#pragma unroll 8
      for (int r = 0; r < PS_REP; ++r) {
        s += psumL[r * 128 + tid];
        q += psqL[r * 128 + tid];
      }
      float mu = s / (float)n;
      float var = q / (float)n - mu * mu;
      float rs = rsqrtf(var + EPSBN);
      float sc = gg[tid] * rs;
      sc_s[tid] = sc;
      sh_s[tid] = be[tid] - mu * sc;
    }
    __syncthreads();
  }

  for (int it = 0; it < 8; ++it) {
    int idx = tid + it * 256;
    int r = idx >> 5, c4 = idx & 31;
    int rrow = row0 + r;
    int row = (rrow >= n) ? (n - 1) : rrow;
    float4 v = *(const float4*)(in + (size_t)row * 128 + c4 * 4);
    if (XFORM == 1) {
      float4 sc = *(const float4*)(sc_s + c4 * 4);
      float4 sh = *(const float4*)(sh_s + c4 * 4);
      v.x = fmaxf(v.x * sc.x + sh.x, 0.f);
      v.y = fmaxf(v.y * sc.y + sh.y, 0.f);
      v.z = fmaxf(v.z * sc.z + sh.z, 0.f);
      v.w = fmaxf(v.w * sc.w + sh.w, 0.f);
    }
    if (XFORM == 2) {
      float4 sc = *(const float4*)(sc_s + c4 * 4);
      float4 sh = *(const float4*)(sh_s + c4 * 4);
      float4 hv = *(const float4*)(hres + (size_t)row * 128 + c4 * 4);
      v.x = v.x * sc.x + sh.x + hv.x;
      v.y = v.y * sc.y + sh.y + hv.y;
      v.z = v.z * sc.z + sh.z + hv.z;
      v.w = v.w * sc.w + sh.w + hv.w;
      if (rrow < n) *(float4*)(hres + (size_t)row * 128 + c4 * 4) = v;
    }
    f16x4 hv16;
    hv16[0] = (_Float16)v.x; hv16[1] = (_Float16)v.y;
    hv16[2] = (_Float16)v.z; hv16[3] = (_Float16)v.w;
    *(f16x4*)(Ap + ((r * 256 + c4 * 8) ^ ((r & 7) << 4))) = hv16;
  }
  for (int it = 0; it < 8; ++it) {
    int idx = tid + it * 256;
    int col = idx >> 4, k8 = idx & 15;
    f16x8 v = *(const f16x8*)(wt + col * 128 + k8 * 8);
    *(f16x8*)(Bp + ((col * 256 + k8 * 16) ^ ((col & 7) << 4))) = v;
  }
  __syncthreads();

  f32x4 acc[8];
#pragma unroll
  for (int ct = 0; ct < 8; ++ct) acc[ct] = (f32x4){0.f, 0.f, 0.f, 0.f};

  int arow = rt * 16 + (lane & 15);
  int kc = (lane >> 4) * 16;
#pragma unroll
  for (int ks = 0; ks < 4; ++ks) {
    int kb = ks * 64;
    f16x8 a = *(f16x8*)(Ap + ((arow * 256 + kb + kc) ^ ((arow & 7) << 4)));
#pragma unroll
    for (int ct = 0; ct < 8; ++ct) {
      int bcol = ct * 16 + (lane & 15);
      f16x8 b = *(f16x8*)(Bp + ((bcol * 256 + kb + kc) ^ ((bcol & 7) << 4)));
      acc[ct] = __builtin_amdgcn_mfma_f32_16x16x32_f16(a, b, acc[ct], 0, 0, 0);
    }
  }

  int orow0 = row0 + rt * 16 + (lane >> 4) * 4;
#pragma unroll
  for (int ct = 0; ct < 8; ++ct) {
    int col = ct * 16 + (lane & 15);
#pragma unroll
    for (int r = 0; r < 4; ++r) {
      int row = orow0 + r;
      if (row < n) outh[(size_t)row * 128 + col] = (_Float16)acc[ct][r];
    }
  }
}

// ---------- edge aggregation: wave-per-node, quad-edge lane-split gather ----------
// 4 groups of 16 lanes; each lane loads f16x8 (16B) -> one VMEM instr = 4 edge rows.
// padded CSR (multiple of 8 edges/node, pad w=0) -> branch-free 8-edge loop.
__global__ __launch_bounds__(256) void k_agg(const _Float16* __restrict__ hw,
                                             const int* __restrict__ prow,
                                             const int4* __restrict__ csr4,
                                             const float* __restrict__ dinv,
                                             const float* __restrict__ bias,
                                             float* __restrict__ out,
                                             float* __restrict__ psumL, int n) {
  int wave = threadIdx.x >> 6;
  int lane = threadIdx.x & 63;
  int grp = lane >> 4;   // 0..3
  int l16 = lane & 15;   // 0..15
  int node = blockIdx.x * 4 + wave;
  float a[8];
#pragma unroll
  for (int j = 0; j < 8; ++j) a[j] = 0.f;

  if (node < n) {
    float b8[8];
#pragma unroll
    for (int j = 0; j < 8; ++j) b8[j] = 0.f;
    int q0 = prow[node] >> 1, q1 = prow[node + 1] >> 1;  // int4 indices (2 edges each)
    for (int q = q0; q < q1; q += 4) {  // 8 edges per iter
      int4 p0 = csr4[q], p1 = csr4[q + 1], p2 = csr4[q + 2], p3 = csr4[q + 3];
      int4 pa = (grp & 2) ? p1 : p0;
      int4 pb = (grp & 2) ? p3 : p2;
      int sa = (grp & 1) ? pa.z : pa.x;
      float wa = __int_as_float((grp & 1) ? pa.w : pa.y);
      int sb = (grp & 1) ? pb.z : pb.x;
      float wb = __int_as_float((grp & 1) ? pb.w : pb.y);
      f16x8 va = *(const f16x8*)(hw + (size_t)sa * 128 + l16 * 8);
      f16x8 vb = *(const f16x8*)(hw + (size_t)sb * 128 + l16 * 8);
#pragma unroll
      for (int j = 0; j < 8; ++j) {
        a[j] += wa * (float)va[j];
        b8[j] += wb * (float)vb[j];
      }
    }
#pragma unroll
    for (int j = 0; j < 8; ++j) a[j] += b8[j];
    // reduce across the 4 groups (lanes differ in bits 4,5)
#pragma unroll
    for (int j = 0; j < 8; ++j) {
      a[j] += __shfl_xor(a[j], 16);
      a[j] += __shfl_xor(a[j], 32);
    }
    float dn = dinv[node];
    float sn = dn * dn;
    f16x8 v = *(const f16x8*)(hw + (size_t)node * 128 + l16 * 8);
    float4 bb0 = *(const float4*)(bias + l16 * 8);
    float4 bb1 = *(const float4*)(bias + l16 * 8 + 4);
    a[0] += sn * (float)v[0] + bb0.x;
    a[1] += sn * (float)v[1] + bb0.y;
    a[2] += sn * (float)v[2] + bb0.z;
    a[3] += sn * (float)v[3] + bb0.w;
    a[4] += sn * (float)v[4] + bb1.x;
    a[5] += sn * (float)v[5] + bb1.y;
    a[6] += sn * (float)v[6] + bb1.z;
    a[7] += sn * (float)v[7] + bb1.w;
    if (grp == 0) {
      *(float4*)(out + (size_t)node * 128 + l16 * 8) = make_float4(a[0], a[1], a[2], a[3]);
      *(float4*)(out + (size_t)node * 128 + l16 * 8 + 4) = make_float4(a[4], a[5], a[6], a[7]);
    }
  }
  // fused BN stats: LDS reduce over 4 waves, replicated atomics into layer slab
  __shared__ float ss[4][128];
  __shared__ float sq[4][128];
  if (grp == 0) {
    bool live = (node < n);
#pragma unroll
    for (int j = 0; j < 8; ++j) {
      float v = live ? a[j] : 0.f;
      ss[wave][l16 * 8 + j] = v;
      sq[wave][l16 * 8 + j] = v * v;
    }
  }
  __syncthreads();
  int t = threadIdx.x;
  if (t < 128) {
    float s = (ss[0][t] + ss[1][t]) + (ss[2][t] + ss[3][t]);
    float q = (sq[0][t] + sq[1][t]) + (sq[2][t] + sq[3][t]);
    int rep = blockIdx.x & (PS_REP - 1);
    atomicAdd(&psumL[rep * 128 + t], s);
    atomicAdd(&psumL[PS_REP * 128 + rep * 128 + t], q);
  }
}

// ---------- pooling (absorbs final BN2+residual): batch sorted -> segment reduction ----------
#define PCHUNK 128
__global__ __launch_bounds__(128) void k_pool(const float* __restrict__ h,
                                              const float* __restrict__ t2,
                                              const float* __restrict__ psumL,
                                              const float* __restrict__ gg,
                                              const float* __restrict__ be,
                                              const int* __restrict__ batch,
                                              float* __restrict__ sums,
                                              unsigned* __restrict__ maxenc,
                                              int* __restrict__ cnt, int n) {
  int c = threadIdx.x;
  __shared__ float sc_s[128], sh_s[128];
  {
    const float* psqL = psumL + PS_REP * 128;
    float s = 0.f, q = 0.f;
#pragma unroll 8
    for (int r = 0; r < PS_REP; ++r) {
      s += psumL[r * 128 + c];
      q += psqL[r * 128 + c];
    }
    float mu = s / (float)n;
    float var = q / (float)n - mu * mu;
    float rs = rsqrtf(var + EPSBN);
    float sc = gg[c] * rs;
    sc_s[c] = sc;
    sh_s[c] = be[c] - mu * sc;
  }
  __syncthreads();
  float scc = sc_s[c], shc = sh_s[c];

  int start = blockIdx.x * PCHUNK;
  if (start >= n) return;
  int end = start + PCHUNK;
  if (end > n) end = n;
  int cur = batch[start];
  float s = 0.f, mx = -FLT_MAX;
  int runlen = 0;
  for (int i = start; i < end; ++i) {
    int b = batch[i];
    if (b != cur) {
      atomicAdd(&sums[cur * 128 + c], s);
      atomicMax(&maxenc[cur * 128 + c], enc_f(mx));
      if (c == 0) atomicAdd(&cnt[cur], runlen);
      s = 0.f; mx = -FLT_MAX; runlen = 0; cur = b;
    }
    float v = h[(size_t)i * 128 + c] + scc * t2[(size_t)i * 128 + c] + shc;
    s += v;
    mx = fmaxf(mx, v);
    runlen++;
  }
  atomicAdd(&sums[cur * 128 + c], s);
  atomicMax(&maxenc[cur * 128 + c], enc_f(mx));
  if (c == 0) atomicAdd(&cnt[cur], runlen);
}

// ---------- readout MLP ----------
__global__ __launch_bounds__(256) void k_readout(const float* __restrict__ sums,
                                                 const unsigned* __restrict__ maxenc,
                                                 const int* __restrict__ cnt,
                                                 const float* __restrict__ Wa,
                                                 const float* __restrict__ ba,
                                                 const float* __restrict__ Wb,
                                                 const float* __restrict__ bb,
                                                 const float* __restrict__ Wc,
                                                 const float* __restrict__ bc,
                                                 float* __restrict__ out) {
  int g = blockIdx.x;
  int t = threadIdx.x;
  __shared__ float z[384];
  __shared__ float za[256];
  __shared__ float zb[128];
  float c = (float)(cnt[g] > 1 ? cnt[g] : 1);
  if (t < 128) {
    float s = sums[g * 128 + t];
    z[t] = s / c;
    z[128 + t] = dec_f(maxenc[g * 128 + t]);
    z[256 + t] = s;
  }
  __syncthreads();
  float accA = ba[t];
  for (int k = 0; k < 384; k++) accA += z[k] * Wa[k * 256 + t];
  za[t] = fmaxf(accA, 0.f);
  __syncthreads();
  if (t < 128) {
    float accB = bb[t];
    for (int k = 0; k < 256; k++) accB += za[k] * Wb[k * 128 + t];
    zb[t] = fmaxf(accB, 0.f);
  }
  __syncthreads();
  if (t < 64) {
    float p = zb[t] * Wc[t] + zb[t + 64] * Wc[t + 64];
    for (int off = 32; off > 0; off >>= 1) p += __shfl_down(p, off);
    if (t == 0) out[g] = p + bc[0];
  }
}

extern "C" void kernel_launch(void* const* d_in, const int* in_sizes, int n_in,
                              void* d_out, int out_size, void* d_ws, size_t ws_size,
                              hipStream_t stream) {
  const float* x   = (const float*)d_in[0];
  const int* edge  = (const int*)d_in[1];
  const int* batch = (const int*)d_in[2];
  const float* Wp  = (const float*)d_in[3];
  const float* bp  = (const float*)d_in[4];
  const float* W1  = (const float*)d_in[5];
  const float* b1  = (const float*)d_in[6];
  const float* g1  = (const float*)d_in[7];
  const float* be1 = (const float*)d_in[8];
  const float* W2  = (const float*)d_in[9];
  const float* b2  = (const float*)d_in[10];
  const float* g2  = (const float*)d_in[11];
  const float* be2 = (const float*)d_in[12];
  const float* Wa  = (const float*)d_in[13];
  const float* ba  = (const float*)d_in[14];
  const float* Wb  = (const float*)d_in[15];
  const float* bbp = (const float*)d_in[16];
  const float* Wc  = (const float*)d_in[17];
  const float* bc  = (const float*)d_in[18];
  float* out = (float*)d_out;

  const int N = in_sizes[0] / 128;
  const int E = in_sizes[1] / 2;
  const int* esrc = edge;
  const int* edst = edge + E;

  char* p = (char*)d_ws;
  auto carve = [&](size_t bytes) {
    char* r = p;
    p += (bytes + 255) & ~(size_t)255;
    return (void*)r;
  };
  float* h    = (float*)carve((size_t)N * 128 * 4);
  _Float16* t1h = (_Float16*)carve((size_t)N * 128 * 2);
  float* t2   = (float*)carve((size_t)N * 128 * 4);
  int2* csr_sw = (int2*)carve(((size_t)E + 8 * (size_t)N) * 8);  // padded CSR
  int* deg     = (int*)carve((size_t)N * 4);
  float* dinv  = (float*)carve((size_t)N * 4);
  int* prow    = (int*)carve((size_t)(N + 1) * 4);
  int* cursor  = (int*)carve((size_t)N * 4);
  int* bsum    = (int*)carve(512 * 4);
  float* slab  = (float*)carve((size_t)16 * SLABF * 4);  // 16 BN slabs
  float* pools = (float*)carve((size_t)NGRAPH * 128 * 4);
  unsigned* poolm = (unsigned*)carve((size_t)NGRAPH * 128 * 4);
  int* poolc      = (int*)carve(NGRAPH * 4);
  _Float16* wt16  = (_Float16*)carve((size_t)17 * 128 * 128 * 2);

  const int NB = (N + 255) / 256;

  hipMemsetAsync(deg, 0, (size_t)N * 4, stream);
  hipMemsetAsync(cursor, 0, (size_t)N * 4, stream);
  hipMemsetAsync(slab, 0, (size_t)16 * SLABF * 4, stream);
  hipMemsetAsync(pools, 0, (size_t)NGRAPH * 128 * 4, stream);
  hipMemsetAsync(poolm, 0, (size_t)NGRAPH * 128 * 4, stream);
  hipMemsetAsync(poolc, 0, (size_t)NGRAPH * 4, stream);

  k_deg<<<(E + 255) / 256, 256, 0, stream>>>(edst, deg, E);
  k_dinv<<<NB, 256, 0, stream>>>(deg, dinv, N);
  k_scanA<<<NB, 256, 0, stream>>>(deg, prow, bsum, N);
  k_scanB<<<1, 512, 0, stream>>>(bsum, NB);
  k_scanC<<<NB, 256, 0, stream>>>(prow, bsum, deg, N);
  k_fill<<<(E + 255) / 256, 256, 0, stream>>>(esrc, edst, dinv, prow, cursor, csr_sw, E);
  k_pad<<<NB, 256, 0, stream>>>(deg, prow, csr_sw, N);
  k_wprep<<<17, 256, 0, stream>>>(W1, W2, Wp, wt16);

  const int GB = (N + 63) / 64;
  const int AB = (N + 3) / 4;
  const int PB = (N + PCHUNK - 1) / PCHUNK;

  k_gemmp<<<GB, 256, 0, stream>>>(x, wt16 + (size_t)16 * 16384, bp, h, N);
  k_gemmh<0><<<GB, 256, 0, stream>>>(h, wt16, nullptr, nullptr, nullptr, nullptr, t1h, N);

  for (int l = 0; l < 8; l++) {
    const _Float16* w2t = wt16 + (size_t)(l * 2 + 1) * 16384;
    float* slab1 = slab + (size_t)(2 * l) * SLABF;
    float* slab2 = slab + (size_t)(2 * l + 1) * SLABF;
    k_agg<<<AB, 256, 0, stream>>>(t1h, prow, (const int4*)csr_sw, dinv, b1 + l * 128, t2, slab1, N);
    k_gemmh<1><<<GB, 256, 0, stream>>>(t2, w2t, slab1, g1 + l * 128, be1 + l * 128, nullptr, t1h, N);
    k_agg<<<AB, 256, 0, stream>>>(t1h, prow, (const int4*)csr_sw, dinv, b2 + l * 128, t2, slab2, N);
    if (l < 7) {
      const _Float16* w1n = wt16 + (size_t)((l + 1) * 2) * 16384;
      k_gemmh<2><<<GB, 256, 0, stream>>>(t2, w1n, slab2, g2 + l * 128, be2 + l * 128, h, t1h, N);
    }
  }

  k_pool<<<PB, 128, 0, stream>>>(h, t2, slab + (size_t)15 * SLABF, g2 + 7 * 128, be2 + 7 * 128,
                                 batch, pools, poolm, poolc, N);
  k_readout<<<NGRAPH, 256, 0, stream>>>(pools, poolm, poolc, Wa, ba, Wb, bbp, Wc, bc, out);
}